// Round 20
// baseline (76.291 us; speedup 1.0000x reference)
//
#include <hip/hip_runtime.h>

#define B_ 8
#define C_ 128
#define H_ 64
#define W_ 64
#define O_ 128
#define F_ 18
#define K2_ 9
#define HW_ 4096
#define CK2_ 1152

#define WR_ 10              // window rows (4-row tile + halo 3/3)
#define WC_ 22              // window cols (16-col tile + halo 3/3)

typedef __attribute__((ext_vector_type(8))) short short8_t;
typedef __attribute__((ext_vector_type(4))) float f32x4_t;
typedef __attribute__((ext_vector_type(2))) float f32x2_t;
typedef __attribute__((ext_vector_type(4))) unsigned int uint4_t;

__device__ inline short bf16r(float f) {
  unsigned u = __builtin_bit_cast(unsigned, f);
  u += 0x7FFFu + ((u >> 16) & 1u);     // round-to-nearest-even
  return (short)(u >> 16);
}
// packed f32 math (VOP3P, CDNA3+)
__device__ inline f32x2_t pk_mul(f32x2_t a, f32x2_t b) {
  f32x2_t d;
  asm("v_pk_mul_f32 %0, %1, %2" : "=v"(d) : "v"(a), "v"(b));
  return d;
}
__device__ inline f32x2_t pk_fma(f32x2_t a, f32x2_t b, f32x2_t c) {
  f32x2_t d;
  asm("v_pk_fma_f32 %0, %1, %2, %3" : "=v"(d) : "v"(a), "v"(b), "v"(c));
  return d;
}
// {lo bf16 as f32, hi bf16 as f32 (raw: low bits = harmless mantissa noise)}
__device__ inline f32x2_t bfpair(unsigned u) {
  return (f32x2_t){__builtin_bit_cast(float, u << 16),
                   __builtin_bit_cast(float, u)};
}

// ---------------- merged prep (ALL bf16 — r12 verbatim) ----------------
__global__ __launch_bounds__(256) void prep_all_kernel(
    const float* __restrict__ w, const float* __restrict__ w_off,
    const float* __restrict__ x,
    short* __restrict__ w_bt2, short* __restrict__ w_ot2,
    short* __restrict__ x_t) {
  __shared__ float tile[128][65];
  int bid = blockIdx.x, t = threadIdx.x;
  if (bid < 576) {
    int i = bid * 256 + t;               // 0..147455 exact
    int kk2 = i & 31, o = (i >> 5) & 127, ks = i >> 12;
    w_bt2[i] = bf16r(w[(o * C_ + (ks & 3) * 32 + kk2) * K2_ + (ks >> 2)]);
  } else if (bid < 720) {
    int i = (bid - 576) * 256 + t;       // 0..36863 exact
    int kk2 = i & 31, f = (i >> 5) & 31, ks = i >> 10;
    w_ot2[i] = (f < F_) ? bf16r(w_off[(f * C_ + (ks & 3) * 32 + kk2) * K2_ + (ks >> 2)])
                        : (short)0;
  } else {
    int xb_id = bid - 720;               // 0..511
    int b = xb_id >> 6;
    int p_base = (xb_id & 63) << 6;
    const float* xb = x + ((long)b << 19);
#pragma unroll
    for (int i = 0; i < 32; ++i) {
      int idx = (i << 8) + t;
      int c = idx >> 6, p = idx & 63;
      tile[c][p] = xb[((long)c << 12) + p_base + p];
    }
    __syncthreads();
#pragma unroll
    for (int i = 0; i < 32; ++i) {
      int idx = (i << 8) + t;
      int p = idx >> 7, c = idx & 127;
      x_t[(((long)(b << 12) + p_base + p) << 7) + c] = bf16r(tile[c][p]);
    }
  }
}

// LDS chunk read: pixel = 256B, 16B chunks XOR-swizzled by pix&15
__device__ inline short8_t lds16(const short* xs, int pix, int ch) {
  return *(const short8_t*)(xs + (pix << 7) + ((ch ^ (pix & 15)) << 3));
}

// ---------------- fused kernel (O-split 16-wave, 8 waves/SIMD) --------------
// block = 1024 threads (16 waves) = 4x16 output tile of one batch.
// Waves: (row=wv&3, g=(wv>>2)&1 K-half, h=wv>>3 O-half). Each wave: 16 pos,
// 2 s-chunks (half K), 4 o-frags (half O) -> acc[4] = 16 VGPR, fits 64-reg
// budget at 8 waves/SIMD. 2 blocks/CU (61.4KB LDS, 2048 thr/CU = max),
// grid 512 = exactly 2/CU, tail-free. Sampling duplicated across h (VALU has
// headroom); Phase A on h=0 waves only; cross-g reduction per (row,h) zone.
__global__ __launch_bounds__(1024, 8) void fused_deform_kernel(
    const short* __restrict__ x_t, const short* __restrict__ w_ot2,
    const float* __restrict__ b_off, const short* __restrict__ w_bt2,
    float* __restrict__ out) {
  __shared__ short xs[WR_ * WC_ * 128];  // 56320 B ; reused as f32 red buffer
  __shared__ float offs[4][16][20];      // 5120 B  ; total 61440 <= 64KB

  int tid = threadIdx.x;
  int wv = tid >> 6, lane = tid & 63;
  int row = wv & 3, g = (wv >> 2) & 1, h = wv >> 3;
  int fr = lane & 15, q = lane >> 4;
  int bid = (int)blockIdx.x;
  int b = bid & 7;                       // batch per XCD
  int tile_id = bid >> 3;                // 0..63
  int ho0 = (tile_id >> 2) << 2;         // 4-row strips
  int x0b = (tile_id & 3) << 4;          // 16-col strips
  int ys  = min(max(ho0 - 3, 0), H_ - WR_);   // full 10-row window in-image
  int xsL = min(max(x0b - 3, 0), W_ - WC_);   // full 22-col window in-image
  int ye2 = ys + WR_ - 1, xe2 = xsL + WC_ - 1;

  const short* xtb = x_t + ((long)b << 19);

  // -------- stage window: 10*22 pixels * 16 chunks = 3520 chunks --------
#pragma unroll
  for (int i = 0; i < 4; ++i) {
    int ci = (i << 10) + tid;
    if (ci < WR_ * WC_ * 16) {
      int pix = ci >> 4, ch = ci & 15;
      int yr = pix / WC_, xr = pix - yr * WC_;
      short8_t v = *(const short8_t*)(xtb + ((((ys + yr) << 6) + xsL + xr) << 7) + (ch << 3));
      *(short8_t*)(xs + (pix << 7) + ((ch ^ (pix & 15)) << 3)) = v;
    }
  }
  __syncthreads();

  int ho = ho0 + row;
  int wo = x0b + fr;

  // -------- Phase A: offset conv via bf16 MFMA, K-split over g, h=0 only ----
  {
    f32x4_t oacc0 = (f32x4_t){0.f, 0.f, 0.f, 0.f};
    f32x4_t oacc1 = (f32x4_t){0.f, 0.f, 0.f, 0.f};
    if (h == 0) {
#pragma unroll
      for (int kt = 0; kt < 9; ++kt) {
        int y = ho + kt / 3 - 1, xx = wo + kt % 3 - 1;
        bool ok = (y >= 0) & (y < H_) & (xx >= 0) & (xx < W_);
        int yc = min(max(y, 0), H_ - 1), xc = min(max(xx, 0), W_ - 1);
        int pixA = (yc - ys) * WC_ + (xc - xsL);
#pragma unroll
        for (int sh = 0; sh < 2; ++sh) {
          int s = (g << 1) | sh;
          short8_t bfv = lds16(xs, pixA, (s << 2) + q);
          if (!ok) bfv = (short8_t){0, 0, 0, 0, 0, 0, 0, 0};
          int ks = (kt << 2) + s;
          short8_t a0 = *(const short8_t*)(w_ot2 + (((ks << 5) + fr) << 5) + (q << 3));
          short8_t a1 = *(const short8_t*)(w_ot2 + (((ks << 5) + 16 + fr) << 5) + (q << 3));
          oacc0 = __builtin_amdgcn_mfma_f32_16x16x32_bf16(a0, bfv, oacc0, 0, 0, 0);
          oacc1 = __builtin_amdgcn_mfma_f32_16x16x32_bf16(a1, bfv, oacc1, 0, 0, 0);
        }
      }
      if (g == 0) {
#pragma unroll
        for (int r = 0; r < 4; ++r) {
          int f0 = (q << 2) + r;
          offs[row][fr][f0] = oacc0[r] + b_off[f0];
        }
        if (q == 0) {
          offs[row][fr][16] = oacc1[0] + b_off[16];
          offs[row][fr][17] = oacc1[1] + b_off[17];
        }
      }
    }
    __syncthreads();
    if (h == 0 && g == 1) {
#pragma unroll
      for (int r = 0; r < 4; ++r) {
        int f0 = (q << 2) + r;
        offs[row][fr][f0] += oacc0[r];
      }
      if (q == 0) {
        offs[row][fr][16] += oacc1[0];
        offs[row][fr][17] += oacc1[1];
      }
    }
  }
  __syncthreads();

  // -------- Phase B: sampling (2 s-chunks) + half-O MFMA --------
  f32x4_t acc[4];
#pragma unroll
  for (int nf = 0; nf < 4; ++nf) acc[nf] = (f32x4_t){0.f, 0.f, 0.f, 0.f};

#pragma unroll
  for (int kt = 0; kt < 9; ++kt) {
    float oy = offs[row][fr][2 * kt];
    float ox = offs[row][fr][2 * kt + 1];

    float py = (float)(ho + kt / 3 - 1) + oy;
    float px = (float)(wo + kt % 3 - 1) + ox;
    float fy0 = floorf(py), fx0 = floorf(px);
    float dy = py - fy0, dx = px - fx0;
    int y0 = (int)fy0, x0 = (int)fx0;
    int y1 = y0 + 1, x1 = x0 + 1;
    float my0 = (y0 >= 0 && y0 < H_) ? 1.f : 0.f;
    float my1 = (y1 >= 0 && y1 < H_) ? 1.f : 0.f;
    float mx0 = (x0 >= 0 && x0 < W_) ? 1.f : 0.f;
    float mx1 = (x1 >= 0 && x1 < W_) ? 1.f : 0.f;
    float w00 = (1.f - dy) * (1.f - dx) * my0 * mx0;
    float w01 = (1.f - dy) * dx * my0 * mx1;
    float w10 = dy * (1.f - dx) * my1 * mx0;
    float w11 = dy * dx * my1 * mx1;
    int y0c = min(max(y0, 0), H_ - 1), y1c = min(max(y1, 0), H_ - 1);
    int x0c = min(max(x0, 0), W_ - 1), x1c = min(max(x1, 0), W_ - 1);
    int p00 = (y0c - ys) * WC_ + (x0c - xsL), p01 = p00 + (x1c - x0c);
    int p10 = (y1c - ys) * WC_ + (x0c - xsL), p11 = p10 + (x1c - x0c);

    // packed corner-weight pairs (same weight in both halves)
    f32x2_t w00p = (f32x2_t){w00, w00}, w01p = (f32x2_t){w01, w01};
    f32x2_t w10p = (f32x2_t){w10, w10}, w11p = (f32x2_t){w11, w11};

    short8_t v00[2], v01[2], v10[2], v11[2];
    unsigned long long bad =
        __ballot((y0c < ys) || (y1c > ye2) || (x0c < xsL) || (x1c > xe2));
    if (bad == 0ULL) {
#pragma unroll
      for (int sh = 0; sh < 2; ++sh) {
        int s = (g << 1) | sh;
        int ch = (s << 2) + q;
        v00[sh] = lds16(xs, p00, ch);
        v01[sh] = lds16(xs, p01, ch);
        v10[sh] = lds16(xs, p10, ch);
        v11[sh] = lds16(xs, p11, ch);
      }
    } else {                             // rare fallback: global gathers
      const short* g00 = xtb + (((y0c << 6) + x0c) << 7);
      const short* g01 = xtb + (((y0c << 6) + x1c) << 7);
      const short* g10 = xtb + (((y1c << 6) + x0c) << 7);
      const short* g11 = xtb + (((y1c << 6) + x1c) << 7);
#pragma unroll
      for (int sh = 0; sh < 2; ++sh) {
        int s = (g << 1) | sh;
        int c0 = (s << 5) + (q << 3);
        v00[sh] = *(const short8_t*)(g00 + c0);
        v01[sh] = *(const short8_t*)(g01 + c0);
        v10[sh] = *(const short8_t*)(g10 + c0);
        v11[sh] = *(const short8_t*)(g11 + c0);
      }
    }

#pragma unroll
    for (int sh = 0; sh < 2; ++sh) {
      int s = (g << 1) | sh;
      uint4_t u00 = __builtin_bit_cast(uint4_t, v00[sh]);
      uint4_t u01 = __builtin_bit_cast(uint4_t, v01[sh]);
      uint4_t u10 = __builtin_bit_cast(uint4_t, v10[sh]);
      uint4_t u11 = __builtin_bit_cast(uint4_t, v11[sh]);
      uint4_t sfu;
#pragma unroll
      for (int d = 0; d < 4; ++d) {
        // packed blend: {lo, hi} lanes at once; hi uses raw-bits trick
        f32x2_t r = pk_mul(bfpair(u00[d]), w00p);
        r = pk_fma(bfpair(u01[d]), w01p, r);
        r = pk_fma(bfpair(u10[d]), w10p, r);
        r = pk_fma(bfpair(u11[d]), w11p, r);
        unsigned p;
        asm("v_cvt_pk_bf16_f32 %0, %1, %2" : "=v"(p) : "v"(r[0]), "v"(r[1]));
        sfu[d] = p;
      }
      short8_t sf = __builtin_bit_cast(short8_t, sfu);
      int ks = (kt << 2) + s;
      const short* wp = w_bt2 + (((ks << 7) + (h << 6) + fr) << 5) + (q << 3);
#pragma unroll
      for (int nf = 0; nf < 4; ++nf) {
        short8_t wf = *(const short8_t*)(wp + (nf << 9));   // +nf*16 o-rows
        acc[nf] = __builtin_amdgcn_mfma_f32_16x16x32_bf16(wf, sf, acc[nf], 0, 0, 0);
      }
    }
  }

  // -------- cross-g reduction through LDS (reuse xs), per (row,h) zone ------
  __syncthreads();                       // xs staging no longer needed
  float* red = (float*)xs;               // 8 zones x [16][68] floats = 34816 B
  int zone = (row << 1) + h;
  int ri = zone * 1088 + fr * 68 + (q << 2);
  if (g == 1) {
#pragma unroll
    for (int nf = 0; nf < 4; ++nf) *(f32x4_t*)&red[ri + (nf << 4)] = acc[nf];
  }
  __syncthreads();
  if (g == 0) {
    float* ob = out + ((long)(b * O_) << 12) + (ho << 6) + wo;
#pragma unroll
    for (int nf = 0; nf < 4; ++nf) {
      f32x4_t other = *(const f32x4_t*)&red[ri + (nf << 4)];
#pragma unroll
      for (int r = 0; r < 4; ++r) {
        ob[(long)(((h << 6) + (nf << 4) + (q << 2) + r)) << 12] = acc[nf][r] + other[r];
      }
    }
  }
}

extern "C" void kernel_launch(void* const* d_in, const int* in_sizes, int n_in,
                              void* d_out, int out_size, void* d_ws, size_t ws_size,
                              hipStream_t stream) {
  const float* x     = (const float*)d_in[0];
  const float* w_off = (const float*)d_in[1];
  const float* b_off = (const float*)d_in[2];
  const float* w     = (const float*)d_in[3];
  float* out = (float*)d_out;

  short* w_bt2 = (short*)d_ws;                                  // 294912 B
  short* w_ot2 = (short*)((char*)d_ws + 294912);                // 73728 B
  short* x_t   = (short*)((char*)d_ws + 294912 + 73728);        // 8388608 B

  prep_all_kernel<<<1232, 256, 0, stream>>>(w, w_off, x, w_bt2, w_ot2, x_t);
  fused_deform_kernel<<<512, 1024, 0, stream>>>(x_t, w_ot2, b_off, w_bt2, out);
}

// Round 21
// 62.710 us; speedup vs baseline: 1.2166x; 1.2166x over previous
//
#include <hip/hip_runtime.h>

#define B_ 8
#define C_ 128
#define H_ 64
#define W_ 64
#define O_ 128
#define F_ 18
#define K2_ 9
#define HW_ 4096
#define CK2_ 1152

#define WR_ 10              // window rows (4-row tile + halo 3/3)
#define WC_ 22              // window cols (16-col tile + halo 3/3)

typedef __attribute__((ext_vector_type(8))) short short8_t;
typedef __attribute__((ext_vector_type(4))) float f32x4_t;
typedef __attribute__((ext_vector_type(2))) float f32x2_t;
typedef __attribute__((ext_vector_type(4))) unsigned int uint4_t;

__device__ inline short bf16r(float f) {
  unsigned u = __builtin_bit_cast(unsigned, f);
  u += 0x7FFFu + ((u >> 16) & 1u);     // round-to-nearest-even
  return (short)(u >> 16);
}
// packed f32 math (VOP3P, CDNA3+)
__device__ inline f32x2_t pk_mul(f32x2_t a, f32x2_t b) {
  f32x2_t d;
  asm("v_pk_mul_f32 %0, %1, %2" : "=v"(d) : "v"(a), "v"(b));
  return d;
}
__device__ inline f32x2_t pk_fma(f32x2_t a, f32x2_t b, f32x2_t c) {
  f32x2_t d;
  asm("v_pk_fma_f32 %0, %1, %2, %3" : "=v"(d) : "v"(a), "v"(b), "v"(c));
  return d;
}
// {lo bf16 as f32, hi bf16 as f32 (raw: low bits = harmless mantissa noise)}
__device__ inline f32x2_t bfpair(unsigned u) {
  return (f32x2_t){__builtin_bit_cast(float, u << 16),
                   __builtin_bit_cast(float, u)};
}

// ---------------- merged prep (ALL bf16 — r12 verbatim) ----------------
__global__ __launch_bounds__(256) void prep_all_kernel(
    const float* __restrict__ w, const float* __restrict__ w_off,
    const float* __restrict__ x,
    short* __restrict__ w_bt2, short* __restrict__ w_ot2,
    short* __restrict__ x_t) {
  __shared__ float tile[128][65];
  int bid = blockIdx.x, t = threadIdx.x;
  if (bid < 576) {
    int i = bid * 256 + t;               // 0..147455 exact
    int kk2 = i & 31, o = (i >> 5) & 127, ks = i >> 12;
    w_bt2[i] = bf16r(w[(o * C_ + (ks & 3) * 32 + kk2) * K2_ + (ks >> 2)]);
  } else if (bid < 720) {
    int i = (bid - 576) * 256 + t;       // 0..36863 exact
    int kk2 = i & 31, f = (i >> 5) & 31, ks = i >> 10;
    w_ot2[i] = (f < F_) ? bf16r(w_off[(f * C_ + (ks & 3) * 32 + kk2) * K2_ + (ks >> 2)])
                        : (short)0;
  } else {
    int xb_id = bid - 720;               // 0..511
    int b = xb_id >> 6;
    int p_base = (xb_id & 63) << 6;
    const float* xb = x + ((long)b << 19);
#pragma unroll
    for (int i = 0; i < 32; ++i) {
      int idx = (i << 8) + t;
      int c = idx >> 6, p = idx & 63;
      tile[c][p] = xb[((long)c << 12) + p_base + p];
    }
    __syncthreads();
#pragma unroll
    for (int i = 0; i < 32; ++i) {
      int idx = (i << 8) + t;
      int p = idx >> 7, c = idx & 127;
      x_t[(((long)(b << 12) + p_base + p) << 7) + c] = bf16r(tile[c][p]);
    }
  }
}

// LDS chunk read: pixel = 256B, 16B chunks XOR-swizzled by pix&15
__device__ inline short8_t lds16(const short* xs, int pix, int ch) {
  return *(const short8_t*)(xs + (pix << 7) + ((ch ^ (pix & 15)) << 3));
}

// ---------------- fused kernel (r18 + offs cached in registers) -------------
// block = 512 threads (8 waves) = 4x16 output tile of one batch.
// Waves: (row=wv&3, g=wv>>2). 2-way K-SPLIT: wave g blends s-chunks {2g,2g+1},
// all 8 O-tiles on half K; partials summed through LDS. Grid 512 = exactly
// 2 blocks/CU (61.4KB LDS) -> tail-free, 4 waves/SIMD. All 18 offsets are
// copied LDS->registers once so per-tap chains start from register state.
__global__ __launch_bounds__(512, 4) void fused_deform_kernel(
    const short* __restrict__ x_t, const short* __restrict__ w_ot2,
    const float* __restrict__ b_off, const short* __restrict__ w_bt2,
    float* __restrict__ out) {
  __shared__ short xs[WR_ * WC_ * 128];  // 56320 B ; reused as f32 red buffer
  __shared__ float offs[4][16][20];      // 5120 B  ; total 61440 <= 64KB

  int tid = threadIdx.x;
  int wv = tid >> 6, lane = tid & 63;
  int row = wv & 3, g = wv >> 2;
  int fr = lane & 15, q = lane >> 4;
  int bid = (int)blockIdx.x;
  int b = bid & 7;                       // batch per XCD
  int tile_id = bid >> 3;                // 0..63
  int ho0 = (tile_id >> 2) << 2;         // 4-row strips
  int x0b = (tile_id & 3) << 4;          // 16-col strips
  int ys  = min(max(ho0 - 3, 0), H_ - WR_);   // full 10-row window in-image
  int xsL = min(max(x0b - 3, 0), W_ - WC_);   // full 22-col window in-image
  int ye2 = ys + WR_ - 1, xe2 = xsL + WC_ - 1;

  const short* xtb = x_t + ((long)b << 19);

  // -------- stage window: 10*22 pixels * 16 chunks = 3520 chunks --------
#pragma unroll
  for (int i = 0; i < 7; ++i) {
    int ci = (i << 9) + tid;
    if (ci < WR_ * WC_ * 16) {
      int pix = ci >> 4, ch = ci & 15;
      int yr = pix / WC_, xr = pix - yr * WC_;
      short8_t v = *(const short8_t*)(xtb + ((((ys + yr) << 6) + xsL + xr) << 7) + (ch << 3));
      *(short8_t*)(xs + (pix << 7) + ((ch ^ (pix & 15)) << 3)) = v;
    }
  }
  __syncthreads();

  int ho = ho0 + row;
  int wo = x0b + fr;

  // -------- Phase A: offset conv via bf16 MFMA, K-split over g --------
  {
    f32x4_t oacc0 = (f32x4_t){0.f, 0.f, 0.f, 0.f};
    f32x4_t oacc1 = (f32x4_t){0.f, 0.f, 0.f, 0.f};
#pragma unroll
    for (int kt = 0; kt < 9; ++kt) {
      int y = ho + kt / 3 - 1, xx = wo + kt % 3 - 1;
      bool ok = (y >= 0) & (y < H_) & (xx >= 0) & (xx < W_);
      int yc = min(max(y, 0), H_ - 1), xc = min(max(xx, 0), W_ - 1);
      int pixA = (yc - ys) * WC_ + (xc - xsL);
#pragma unroll
      for (int sh = 0; sh < 2; ++sh) {
        int s = (g << 1) | sh;
        short8_t bfv = lds16(xs, pixA, (s << 2) + q);
        if (!ok) bfv = (short8_t){0, 0, 0, 0, 0, 0, 0, 0};
        int ks = (kt << 2) + s;
        short8_t a0 = *(const short8_t*)(w_ot2 + (((ks << 5) + fr) << 5) + (q << 3));
        short8_t a1 = *(const short8_t*)(w_ot2 + (((ks << 5) + 16 + fr) << 5) + (q << 3));
        oacc0 = __builtin_amdgcn_mfma_f32_16x16x32_bf16(a0, bfv, oacc0, 0, 0, 0);
        oacc1 = __builtin_amdgcn_mfma_f32_16x16x32_bf16(a1, bfv, oacc1, 0, 0, 0);
      }
    }
    // combine partials: g0 writes (+b_off), barrier, g1 adds.
    if (g == 0) {
#pragma unroll
      for (int r = 0; r < 4; ++r) {
        int f0 = (q << 2) + r;
        offs[row][fr][f0] = oacc0[r] + b_off[f0];
      }
      if (q == 0) {
        offs[row][fr][16] = oacc1[0] + b_off[16];
        offs[row][fr][17] = oacc1[1] + b_off[17];
      }
    }
    __syncthreads();
    if (g == 1) {
#pragma unroll
      for (int r = 0; r < 4; ++r) {
        int f0 = (q << 2) + r;
        offs[row][fr][f0] += oacc0[r];
      }
      if (q == 0) {
        offs[row][fr][16] += oacc1[0];
        offs[row][fr][17] += oacc1[1];
      }
    }
  }
  __syncthreads();

  // -------- copy this thread's 18 offsets LDS -> registers (once) --------
  float ofr[18];
#pragma unroll
  for (int i = 0; i < 18; ++i) ofr[i] = offs[row][fr][i];

  // -------- Phase B: sampling (2 s-chunks per wave) + full-O MFMA --------
  f32x4_t acc[8];
#pragma unroll
  for (int nf = 0; nf < 8; ++nf) acc[nf] = (f32x4_t){0.f, 0.f, 0.f, 0.f};

#pragma unroll
  for (int kt = 0; kt < 9; ++kt) {
    float oy = ofr[2 * kt];
    float ox = ofr[2 * kt + 1];

    float py = (float)(ho + kt / 3 - 1) + oy;
    float px = (float)(wo + kt % 3 - 1) + ox;
    float fy0 = floorf(py), fx0 = floorf(px);
    float dy = py - fy0, dx = px - fx0;
    int y0 = (int)fy0, x0 = (int)fx0;
    int y1 = y0 + 1, x1 = x0 + 1;
    float my0 = (y0 >= 0 && y0 < H_) ? 1.f : 0.f;
    float my1 = (y1 >= 0 && y1 < H_) ? 1.f : 0.f;
    float mx0 = (x0 >= 0 && x0 < W_) ? 1.f : 0.f;
    float mx1 = (x1 >= 0 && x1 < W_) ? 1.f : 0.f;
    float w00 = (1.f - dy) * (1.f - dx) * my0 * mx0;
    float w01 = (1.f - dy) * dx * my0 * mx1;
    float w10 = dy * (1.f - dx) * my1 * mx0;
    float w11 = dy * dx * my1 * mx1;
    int y0c = min(max(y0, 0), H_ - 1), y1c = min(max(y1, 0), H_ - 1);
    int x0c = min(max(x0, 0), W_ - 1), x1c = min(max(x1, 0), W_ - 1);
    int p00 = (y0c - ys) * WC_ + (x0c - xsL), p01 = p00 + (x1c - x0c);
    int p10 = (y1c - ys) * WC_ + (x0c - xsL), p11 = p10 + (x1c - x0c);

    // packed corner-weight pairs (same weight in both halves)
    f32x2_t w00p = (f32x2_t){w00, w00}, w01p = (f32x2_t){w01, w01};
    f32x2_t w10p = (f32x2_t){w10, w10}, w11p = (f32x2_t){w11, w11};

    short8_t v00[2], v01[2], v10[2], v11[2];
    unsigned long long bad =
        __ballot((y0c < ys) || (y1c > ye2) || (x0c < xsL) || (x1c > xe2));
    if (bad == 0ULL) {
#pragma unroll
      for (int sh = 0; sh < 2; ++sh) {
        int s = (g << 1) | sh;
        int ch = (s << 2) + q;
        v00[sh] = lds16(xs, p00, ch);
        v01[sh] = lds16(xs, p01, ch);
        v10[sh] = lds16(xs, p10, ch);
        v11[sh] = lds16(xs, p11, ch);
      }
    } else {                             // rare fallback: global gathers
      const short* g00 = xtb + (((y0c << 6) + x0c) << 7);
      const short* g01 = xtb + (((y0c << 6) + x1c) << 7);
      const short* g10 = xtb + (((y1c << 6) + x0c) << 7);
      const short* g11 = xtb + (((y1c << 6) + x1c) << 7);
#pragma unroll
      for (int sh = 0; sh < 2; ++sh) {
        int s = (g << 1) | sh;
        int c0 = (s << 5) + (q << 3);
        v00[sh] = *(const short8_t*)(g00 + c0);
        v01[sh] = *(const short8_t*)(g01 + c0);
        v10[sh] = *(const short8_t*)(g10 + c0);
        v11[sh] = *(const short8_t*)(g11 + c0);
      }
    }

#pragma unroll
    for (int sh = 0; sh < 2; ++sh) {
      int s = (g << 1) | sh;
      uint4_t u00 = __builtin_bit_cast(uint4_t, v00[sh]);
      uint4_t u01 = __builtin_bit_cast(uint4_t, v01[sh]);
      uint4_t u10 = __builtin_bit_cast(uint4_t, v10[sh]);
      uint4_t u11 = __builtin_bit_cast(uint4_t, v11[sh]);
      uint4_t sfu;
#pragma unroll
      for (int d = 0; d < 4; ++d) {
        // packed blend: {lo, hi} lanes at once; hi uses raw-bits trick
        f32x2_t r = pk_mul(bfpair(u00[d]), w00p);
        r = pk_fma(bfpair(u01[d]), w01p, r);
        r = pk_fma(bfpair(u10[d]), w10p, r);
        r = pk_fma(bfpair(u11[d]), w11p, r);
        unsigned p;
        asm("v_cvt_pk_bf16_f32 %0, %1, %2" : "=v"(p) : "v"(r[0]), "v"(r[1]));
        sfu[d] = p;
      }
      short8_t sf = __builtin_bit_cast(short8_t, sfu);
      int ks = (kt << 2) + s;
      const short* wp = w_bt2 + (((ks << 7) + fr) << 5) + (q << 3);
#pragma unroll
      for (int nf = 0; nf < 8; ++nf) {
        short8_t wf = *(const short8_t*)(wp + (nf << 9));   // +nf*16 o-rows
        acc[nf] = __builtin_amdgcn_mfma_f32_16x16x32_bf16(wf, sf, acc[nf], 0, 0, 0);
      }
    }
  }

  // -------- cross-g reduction through LDS (reuse xs), g0 stores --------
  __syncthreads();                       // xs staging no longer needed
  float* red = (float*)xs;               // [4][16][136] floats = 34816 B
  if (g == 1) {
#pragma unroll
    for (int nf = 0; nf < 8; ++nf) {
      *(f32x4_t*)&red[(row * 16 + fr) * 136 + (nf << 4) + (q << 2)] = acc[nf];
    }
  }
  __syncthreads();
  if (g == 0) {
    float* ob = out + ((long)(b * O_) << 12) + (ho << 6) + wo;
#pragma unroll
    for (int nf = 0; nf < 8; ++nf) {
      f32x4_t other = *(const f32x4_t*)&red[(row * 16 + fr) * 136 + (nf << 4) + (q << 2)];
#pragma unroll
      for (int r = 0; r < 4; ++r) {
        ob[(long)((nf << 4) + (q << 2) + r) << 12] = acc[nf][r] + other[r];
      }
    }
  }
}

extern "C" void kernel_launch(void* const* d_in, const int* in_sizes, int n_in,
                              void* d_out, int out_size, void* d_ws, size_t ws_size,
                              hipStream_t stream) {
  const float* x     = (const float*)d_in[0];
  const float* w_off = (const float*)d_in[1];
  const float* b_off = (const float*)d_in[2];
  const float* w     = (const float*)d_in[3];
  float* out = (float*)d_out;

  short* w_bt2 = (short*)d_ws;                                  // 294912 B
  short* w_ot2 = (short*)((char*)d_ws + 294912);                // 73728 B
  short* x_t   = (short*)((char*)d_ws + 294912 + 73728);        // 8388608 B

  prep_all_kernel<<<1232, 256, 0, stream>>>(w, w_off, x, w_bt2, w_ot2, x_t);
  fused_deform_kernel<<<512, 512, 0, stream>>>(x_t, w_ot2, b_off, w_bt2, out);
}

// Round 22
// 59.981 us; speedup vs baseline: 1.2719x; 1.0455x over previous
//
#include <hip/hip_runtime.h>

#define B_ 8
#define C_ 128
#define H_ 64
#define W_ 64
#define O_ 128
#define F_ 18
#define K2_ 9
#define HW_ 4096
#define CK2_ 1152

#define WR_ 10              // window rows (4-row tile + halo 3/3)
#define WC_ 22              // window cols (16-col tile + halo 3/3)

typedef __attribute__((ext_vector_type(8))) short short8_t;
typedef __attribute__((ext_vector_type(4))) float f32x4_t;
typedef __attribute__((ext_vector_type(2))) float f32x2_t;
typedef __attribute__((ext_vector_type(4))) unsigned int uint4_t;

__device__ inline short bf16r(float f) {
  unsigned u = __builtin_bit_cast(unsigned, f);
  u += 0x7FFFu + ((u >> 16) & 1u);     // round-to-nearest-even
  return (short)(u >> 16);
}
// packed f32 math (VOP3P, CDNA3+)
__device__ inline f32x2_t pk_mul(f32x2_t a, f32x2_t b) {
  f32x2_t d;
  asm("v_pk_mul_f32 %0, %1, %2" : "=v"(d) : "v"(a), "v"(b));
  return d;
}
__device__ inline f32x2_t pk_fma(f32x2_t a, f32x2_t b, f32x2_t c) {
  f32x2_t d;
  asm("v_pk_fma_f32 %0, %1, %2, %3" : "=v"(d) : "v"(a), "v"(b), "v"(c));
  return d;
}
// {lo bf16 as f32, hi bf16 as f32 (raw: low bits = harmless mantissa noise)}
__device__ inline f32x2_t bfpair(unsigned u) {
  return (f32x2_t){__builtin_bit_cast(float, u << 16),
                   __builtin_bit_cast(float, u)};
}

// ---------------- merged prep (ALL bf16) ----------------
__global__ __launch_bounds__(256) void prep_all_kernel(
    const float* __restrict__ w, const float* __restrict__ w_off,
    const float* __restrict__ x,
    short* __restrict__ w_bt2, short* __restrict__ w_ot2,
    short* __restrict__ x_t) {
  __shared__ float tile[128][65];
  int bid = blockIdx.x, t = threadIdx.x;
  if (bid < 576) {
    int i = bid * 256 + t;               // 0..147455 exact
    int kk2 = i & 31, o = (i >> 5) & 127, ks = i >> 12;
    w_bt2[i] = bf16r(w[(o * C_ + (ks & 3) * 32 + kk2) * K2_ + (ks >> 2)]);
  } else if (bid < 720) {
    int i = (bid - 576) * 256 + t;       // 0..36863 exact
    int kk2 = i & 31, f = (i >> 5) & 31, ks = i >> 10;
    w_ot2[i] = (f < F_) ? bf16r(w_off[(f * C_ + (ks & 3) * 32 + kk2) * K2_ + (ks >> 2)])
                        : (short)0;
  } else {
    int xb_id = bid - 720;               // 0..511
    int b = xb_id >> 6;
    int p_base = (xb_id & 63) << 6;
    const float* xb = x + ((long)b << 19);
#pragma unroll
    for (int i = 0; i < 32; ++i) {
      int idx = (i << 8) + t;
      int c = idx >> 6, p = idx & 63;
      tile[c][p] = xb[((long)c << 12) + p_base + p];
    }
    __syncthreads();
#pragma unroll
    for (int i = 0; i < 32; ++i) {
      int idx = (i << 8) + t;
      int p = idx >> 7, c = idx & 127;
      x_t[(((long)(b << 12) + p_base + p) << 7) + c] = bf16r(tile[c][p]);
    }
  }
}

// LDS chunk read: pixel = 256B, 16B chunks XOR-swizzled by pix&15
__device__ inline short8_t lds16(const short* xs, int pix, int ch) {
  return *(const short8_t*)(xs + (pix << 7) + ((ch ^ (pix & 15)) << 3));
}

// ---------------- fused kernel (best-measured configuration) ----------------
// block = 512 threads (8 waves) = 4x16 output tile of one batch.
// Waves: (row=wv&3, g=wv>>2). 2-way K-SPLIT: wave g blends s-chunks {2g,2g+1},
// all 8 O-tiles on half K; partials summed through LDS. Grid 512 = exactly
// 2 blocks/CU (61.4KB LDS) -> tail-free, 4 waves/SIMD.
// NOTE: structure is wedged at ~50us: unified reg use ~128 (=4w/SIMD cap,
// spills at >=6w/SIMD), LDS 61.4KB (2 blocks/CU), 9 serial gather chains.
__global__ __launch_bounds__(512, 4) void fused_deform_kernel(
    const short* __restrict__ x_t, const short* __restrict__ w_ot2,
    const float* __restrict__ b_off, const short* __restrict__ w_bt2,
    float* __restrict__ out) {
  __shared__ short xs[WR_ * WC_ * 128];  // 56320 B ; reused as f32 red buffer
  __shared__ float offs[4][16][20];      // 5120 B  ; total 61440 <= 64KB

  int tid = threadIdx.x;
  int wv = tid >> 6, lane = tid & 63;
  int row = wv & 3, g = wv >> 2;
  int fr = lane & 15, q = lane >> 4;
  int bid = (int)blockIdx.x;
  int b = bid & 7;                       // batch per XCD
  int tile_id = bid >> 3;                // 0..63
  int ho0 = (tile_id >> 2) << 2;         // 4-row strips
  int x0b = (tile_id & 3) << 4;          // 16-col strips
  int ys  = min(max(ho0 - 3, 0), H_ - WR_);   // full 10-row window in-image
  int xsL = min(max(x0b - 3, 0), W_ - WC_);   // full 22-col window in-image
  int ye2 = ys + WR_ - 1, xe2 = xsL + WC_ - 1;

  const short* xtb = x_t + ((long)b << 19);

  // -------- stage window: 10*22 pixels * 16 chunks = 3520 chunks --------
#pragma unroll
  for (int i = 0; i < 7; ++i) {
    int ci = (i << 9) + tid;
    if (ci < WR_ * WC_ * 16) {
      int pix = ci >> 4, ch = ci & 15;
      int yr = pix / WC_, xr = pix - yr * WC_;
      short8_t v = *(const short8_t*)(xtb + ((((ys + yr) << 6) + xsL + xr) << 7) + (ch << 3));
      *(short8_t*)(xs + (pix << 7) + ((ch ^ (pix & 15)) << 3)) = v;
    }
  }
  __syncthreads();

  int ho = ho0 + row;
  int wo = x0b + fr;

  // -------- Phase A: offset conv via bf16 MFMA, K-split over g --------
  {
    f32x4_t oacc0 = (f32x4_t){0.f, 0.f, 0.f, 0.f};
    f32x4_t oacc1 = (f32x4_t){0.f, 0.f, 0.f, 0.f};
#pragma unroll
    for (int kt = 0; kt < 9; ++kt) {
      int y = ho + kt / 3 - 1, xx = wo + kt % 3 - 1;
      bool ok = (y >= 0) & (y < H_) & (xx >= 0) & (xx < W_);
      int yc = min(max(y, 0), H_ - 1), xc = min(max(xx, 0), W_ - 1);
      int pixA = (yc - ys) * WC_ + (xc - xsL);
#pragma unroll
      for (int sh = 0; sh < 2; ++sh) {
        int s = (g << 1) | sh;
        short8_t bfv = lds16(xs, pixA, (s << 2) + q);
        if (!ok) bfv = (short8_t){0, 0, 0, 0, 0, 0, 0, 0};
        int ks = (kt << 2) + s;
        short8_t a0 = *(const short8_t*)(w_ot2 + (((ks << 5) + fr) << 5) + (q << 3));
        short8_t a1 = *(const short8_t*)(w_ot2 + (((ks << 5) + 16 + fr) << 5) + (q << 3));
        oacc0 = __builtin_amdgcn_mfma_f32_16x16x32_bf16(a0, bfv, oacc0, 0, 0, 0);
        oacc1 = __builtin_amdgcn_mfma_f32_16x16x32_bf16(a1, bfv, oacc1, 0, 0, 0);
      }
    }
    // combine partials: g0 writes (+b_off), barrier, g1 adds.
    if (g == 0) {
#pragma unroll
      for (int r = 0; r < 4; ++r) {
        int f0 = (q << 2) + r;
        offs[row][fr][f0] = oacc0[r] + b_off[f0];
      }
      if (q == 0) {
        offs[row][fr][16] = oacc1[0] + b_off[16];
        offs[row][fr][17] = oacc1[1] + b_off[17];
      }
    }
    __syncthreads();
    if (g == 1) {
#pragma unroll
      for (int r = 0; r < 4; ++r) {
        int f0 = (q << 2) + r;
        offs[row][fr][f0] += oacc0[r];
      }
      if (q == 0) {
        offs[row][fr][16] += oacc1[0];
        offs[row][fr][17] += oacc1[1];
      }
    }
  }
  __syncthreads();

  // -------- Phase B: sampling (2 s-chunks per wave) + full-O MFMA --------
  f32x4_t acc[8];
#pragma unroll
  for (int nf = 0; nf < 8; ++nf) acc[nf] = (f32x4_t){0.f, 0.f, 0.f, 0.f};

#pragma unroll
  for (int kt = 0; kt < 9; ++kt) {
    float oy = offs[row][fr][2 * kt];
    float ox = offs[row][fr][2 * kt + 1];

    float py = (float)(ho + kt / 3 - 1) + oy;
    float px = (float)(wo + kt % 3 - 1) + ox;
    float fy0 = floorf(py), fx0 = floorf(px);
    float dy = py - fy0, dx = px - fx0;
    int y0 = (int)fy0, x0 = (int)fx0;
    int y1 = y0 + 1, x1 = x0 + 1;
    float my0 = (y0 >= 0 && y0 < H_) ? 1.f : 0.f;
    float my1 = (y1 >= 0 && y1 < H_) ? 1.f : 0.f;
    float mx0 = (x0 >= 0 && x0 < W_) ? 1.f : 0.f;
    float mx1 = (x1 >= 0 && x1 < W_) ? 1.f : 0.f;
    float w00 = (1.f - dy) * (1.f - dx) * my0 * mx0;
    float w01 = (1.f - dy) * dx * my0 * mx1;
    float w10 = dy * (1.f - dx) * my1 * mx0;
    float w11 = dy * dx * my1 * mx1;
    int y0c = min(max(y0, 0), H_ - 1), y1c = min(max(y1, 0), H_ - 1);
    int x0c = min(max(x0, 0), W_ - 1), x1c = min(max(x1, 0), W_ - 1);
    int p00 = (y0c - ys) * WC_ + (x0c - xsL), p01 = p00 + (x1c - x0c);
    int p10 = (y1c - ys) * WC_ + (x0c - xsL), p11 = p10 + (x1c - x0c);

    // packed corner-weight pairs (same weight in both halves)
    f32x2_t w00p = (f32x2_t){w00, w00}, w01p = (f32x2_t){w01, w01};
    f32x2_t w10p = (f32x2_t){w10, w10}, w11p = (f32x2_t){w11, w11};

    short8_t v00[2], v01[2], v10[2], v11[2];
    unsigned long long bad =
        __ballot((y0c < ys) || (y1c > ye2) || (x0c < xsL) || (x1c > xe2));
    if (bad == 0ULL) {
#pragma unroll
      for (int sh = 0; sh < 2; ++sh) {
        int s = (g << 1) | sh;
        int ch = (s << 2) + q;
        v00[sh] = lds16(xs, p00, ch);
        v01[sh] = lds16(xs, p01, ch);
        v10[sh] = lds16(xs, p10, ch);
        v11[sh] = lds16(xs, p11, ch);
      }
    } else {                             // rare fallback: global gathers
      const short* g00 = xtb + (((y0c << 6) + x0c) << 7);
      const short* g01 = xtb + (((y0c << 6) + x1c) << 7);
      const short* g10 = xtb + (((y1c << 6) + x0c) << 7);
      const short* g11 = xtb + (((y1c << 6) + x1c) << 7);
#pragma unroll
      for (int sh = 0; sh < 2; ++sh) {
        int s = (g << 1) | sh;
        int c0 = (s << 5) + (q << 3);
        v00[sh] = *(const short8_t*)(g00 + c0);
        v01[sh] = *(const short8_t*)(g01 + c0);
        v10[sh] = *(const short8_t*)(g10 + c0);
        v11[sh] = *(const short8_t*)(g11 + c0);
      }
    }

#pragma unroll
    for (int sh = 0; sh < 2; ++sh) {
      int s = (g << 1) | sh;
      uint4_t u00 = __builtin_bit_cast(uint4_t, v00[sh]);
      uint4_t u01 = __builtin_bit_cast(uint4_t, v01[sh]);
      uint4_t u10 = __builtin_bit_cast(uint4_t, v10[sh]);
      uint4_t u11 = __builtin_bit_cast(uint4_t, v11[sh]);
      uint4_t sfu;
#pragma unroll
      for (int d = 0; d < 4; ++d) {
        // packed blend: {lo, hi} lanes at once; hi uses raw-bits trick
        f32x2_t r = pk_mul(bfpair(u00[d]), w00p);
        r = pk_fma(bfpair(u01[d]), w01p, r);
        r = pk_fma(bfpair(u10[d]), w10p, r);
        r = pk_fma(bfpair(u11[d]), w11p, r);
        unsigned p;
        asm("v_cvt_pk_bf16_f32 %0, %1, %2" : "=v"(p) : "v"(r[0]), "v"(r[1]));
        sfu[d] = p;
      }
      short8_t sf = __builtin_bit_cast(short8_t, sfu);
      int ks = (kt << 2) + s;
      const short* wp = w_bt2 + (((ks << 7) + fr) << 5) + (q << 3);
#pragma unroll
      for (int nf = 0; nf < 8; ++nf) {
        short8_t wf = *(const short8_t*)(wp + (nf << 9));   // +nf*16 o-rows
        acc[nf] = __builtin_amdgcn_mfma_f32_16x16x32_bf16(wf, sf, acc[nf], 0, 0, 0);
      }
    }
  }

  // -------- cross-g reduction through LDS (reuse xs), g0 stores --------
  __syncthreads();                       // xs staging no longer needed
  float* red = (float*)xs;               // [4][16][136] floats = 34816 B
  if (g == 1) {
#pragma unroll
    for (int nf = 0; nf < 8; ++nf) {
      *(f32x4_t*)&red[(row * 16 + fr) * 136 + (nf << 4) + (q << 2)] = acc[nf];
    }
  }
  __syncthreads();
  if (g == 0) {
    float* ob = out + ((long)(b * O_) << 12) + (ho << 6) + wo;
#pragma unroll
    for (int nf = 0; nf < 8; ++nf) {
      f32x4_t other = *(const f32x4_t*)&red[(row * 16 + fr) * 136 + (nf << 4) + (q << 2)];
#pragma unroll
      for (int r = 0; r < 4; ++r) {
        ob[(long)((nf << 4) + (q << 2) + r) << 12] = acc[nf][r] + other[r];
      }
    }
  }
}

extern "C" void kernel_launch(void* const* d_in, const int* in_sizes, int n_in,
                              void* d_out, int out_size, void* d_ws, size_t ws_size,
                              hipStream_t stream) {
  const float* x     = (const float*)d_in[0];
  const float* w_off = (const float*)d_in[1];
  const float* b_off = (const float*)d_in[2];
  const float* w     = (const float*)d_in[3];
  float* out = (float*)d_out;

  short* w_bt2 = (short*)d_ws;                                  // 294912 B
  short* w_ot2 = (short*)((char*)d_ws + 294912);                // 73728 B
  short* x_t   = (short*)((char*)d_ws + 294912 + 73728);        // 8388608 B

  prep_all_kernel<<<1232, 256, 0, stream>>>(w, w_off, x, w_bt2, w_ot2, x_t);
  fused_deform_kernel<<<512, 512, 0, stream>>>(x_t, w_ot2, b_off, w_bt2, out);
}

// Round 23
// 59.762 us; speedup vs baseline: 1.2766x; 1.0037x over previous
//
#include <hip/hip_runtime.h>

#define B_ 8
#define C_ 128
#define H_ 64
#define W_ 64
#define O_ 128
#define F_ 18
#define K2_ 9
#define HW_ 4096
#define CK2_ 1152

#define WR_ 10              // window rows (4-row tile + halo 3/3)
#define WC_ 22              // window cols (16-col tile + halo 3/3)

typedef __attribute__((ext_vector_type(8))) short short8_t;
typedef __attribute__((ext_vector_type(4))) float f32x4_t;
typedef __attribute__((ext_vector_type(2))) float f32x2_t;
typedef __attribute__((ext_vector_type(4))) unsigned int uint4_t;

__device__ inline short bf16r(float f) {
  unsigned u = __builtin_bit_cast(unsigned, f);
  u += 0x7FFFu + ((u >> 16) & 1u);     // round-to-nearest-even
  return (short)(u >> 16);
}
// packed f32 math (VOP3P, CDNA3+)
__device__ inline f32x2_t pk_mul(f32x2_t a, f32x2_t b) {
  f32x2_t d;
  asm("v_pk_mul_f32 %0, %1, %2" : "=v"(d) : "v"(a), "v"(b));
  return d;
}
__device__ inline f32x2_t pk_fma(f32x2_t a, f32x2_t b, f32x2_t c) {
  f32x2_t d;
  asm("v_pk_fma_f32 %0, %1, %2, %3" : "=v"(d) : "v"(a), "v"(b), "v"(c));
  return d;
}
// {lo bf16 as f32, hi bf16 as f32 (raw: low bits = harmless mantissa noise)}
__device__ inline f32x2_t bfpair(unsigned u) {
  return (f32x2_t){__builtin_bit_cast(float, u << 16),
                   __builtin_bit_cast(float, u)};
}

// ---------------- merged prep (ALL bf16) ----------------
__global__ __launch_bounds__(256) void prep_all_kernel(
    const float* __restrict__ w, const float* __restrict__ w_off,
    const float* __restrict__ x,
    short* __restrict__ w_bt2, short* __restrict__ w_ot2,
    short* __restrict__ x_t) {
  __shared__ float tile[128][65];
  int bid = blockIdx.x, t = threadIdx.x;
  if (bid < 576) {
    int i = bid * 256 + t;               // 0..147455 exact
    int kk2 = i & 31, o = (i >> 5) & 127, ks = i >> 12;
    w_bt2[i] = bf16r(w[(o * C_ + (ks & 3) * 32 + kk2) * K2_ + (ks >> 2)]);
  } else if (bid < 720) {
    int i = (bid - 576) * 256 + t;       // 0..36863 exact
    int kk2 = i & 31, f = (i >> 5) & 31, ks = i >> 10;
    w_ot2[i] = (f < F_) ? bf16r(w_off[(f * C_ + (ks & 3) * 32 + kk2) * K2_ + (ks >> 2)])
                        : (short)0;
  } else {
    int xb_id = bid - 720;               // 0..511
    int b = xb_id >> 6;
    int p_base = (xb_id & 63) << 6;
    const float* xb = x + ((long)b << 19);
#pragma unroll
    for (int i = 0; i < 32; ++i) {
      int idx = (i << 8) + t;
      int c = idx >> 6, p = idx & 63;
      tile[c][p] = xb[((long)c << 12) + p_base + p];
    }
    __syncthreads();
#pragma unroll
    for (int i = 0; i < 32; ++i) {
      int idx = (i << 8) + t;
      int p = idx >> 7, c = idx & 127;
      x_t[(((long)(b << 12) + p_base + p) << 7) + c] = bf16r(tile[c][p]);
    }
  }
}

// LDS chunk read: pixel = 256B, 16B chunks XOR-swizzled by pix&15
__device__ inline short8_t lds16(const short* xs, int pix, int ch) {
  return *(const short8_t*)(xs + (pix << 7) + ((ch ^ (pix & 15)) << 3));
}

// ---------------- fused kernel (r18 + hoisted escape ballot) ----------------
// block = 512 threads (8 waves) = 4x16 output tile of one batch.
// Waves: (row=wv&3, g=wv>>2). 2-way K-SPLIT. Grid 512 = 2 blocks/CU.
// Phase B: ONE wave-uniform escape ballot over all 9 taps, then either a
// fully BRANCHLESS fast loop (scheduler can overlap taps' ds_reads with
// MFMA) or the per-tap-fallback slow loop (cold, exact semantics).
__global__ __launch_bounds__(512, 4) void fused_deform_kernel(
    const short* __restrict__ x_t, const short* __restrict__ w_ot2,
    const float* __restrict__ b_off, const short* __restrict__ w_bt2,
    float* __restrict__ out) {
  __shared__ short xs[WR_ * WC_ * 128];  // 56320 B ; reused as f32 red buffer
  __shared__ float offs[4][16][20];      // 5120 B  ; total 61440 <= 64KB

  int tid = threadIdx.x;
  int wv = tid >> 6, lane = tid & 63;
  int row = wv & 3, g = wv >> 2;
  int fr = lane & 15, q = lane >> 4;
  int bid = (int)blockIdx.x;
  int b = bid & 7;                       // batch per XCD
  int tile_id = bid >> 3;                // 0..63
  int ho0 = (tile_id >> 2) << 2;         // 4-row strips
  int x0b = (tile_id & 3) << 4;          // 16-col strips
  int ys  = min(max(ho0 - 3, 0), H_ - WR_);   // full 10-row window in-image
  int xsL = min(max(x0b - 3, 0), W_ - WC_);   // full 22-col window in-image
  int ye2 = ys + WR_ - 1, xe2 = xsL + WC_ - 1;

  const short* xtb = x_t + ((long)b << 19);

  // -------- stage window: 10*22 pixels * 16 chunks = 3520 chunks --------
#pragma unroll
  for (int i = 0; i < 7; ++i) {
    int ci = (i << 9) + tid;
    if (ci < WR_ * WC_ * 16) {
      int pix = ci >> 4, ch = ci & 15;
      int yr = pix / WC_, xr = pix - yr * WC_;
      short8_t v = *(const short8_t*)(xtb + ((((ys + yr) << 6) + xsL + xr) << 7) + (ch << 3));
      *(short8_t*)(xs + (pix << 7) + ((ch ^ (pix & 15)) << 3)) = v;
    }
  }
  __syncthreads();

  int ho = ho0 + row;
  int wo = x0b + fr;

  // -------- Phase A: offset conv via bf16 MFMA, K-split over g --------
  {
    f32x4_t oacc0 = (f32x4_t){0.f, 0.f, 0.f, 0.f};
    f32x4_t oacc1 = (f32x4_t){0.f, 0.f, 0.f, 0.f};
#pragma unroll
    for (int kt = 0; kt < 9; ++kt) {
      int y = ho + kt / 3 - 1, xx = wo + kt % 3 - 1;
      bool ok = (y >= 0) & (y < H_) & (xx >= 0) & (xx < W_);
      int yc = min(max(y, 0), H_ - 1), xc = min(max(xx, 0), W_ - 1);
      int pixA = (yc - ys) * WC_ + (xc - xsL);
#pragma unroll
      for (int sh = 0; sh < 2; ++sh) {
        int s = (g << 1) | sh;
        short8_t bfv = lds16(xs, pixA, (s << 2) + q);
        if (!ok) bfv = (short8_t){0, 0, 0, 0, 0, 0, 0, 0};
        int ks = (kt << 2) + s;
        short8_t a0 = *(const short8_t*)(w_ot2 + (((ks << 5) + fr) << 5) + (q << 3));
        short8_t a1 = *(const short8_t*)(w_ot2 + (((ks << 5) + 16 + fr) << 5) + (q << 3));
        oacc0 = __builtin_amdgcn_mfma_f32_16x16x32_bf16(a0, bfv, oacc0, 0, 0, 0);
        oacc1 = __builtin_amdgcn_mfma_f32_16x16x32_bf16(a1, bfv, oacc1, 0, 0, 0);
      }
    }
    // combine partials: g0 writes (+b_off), barrier, g1 adds.
    if (g == 0) {
#pragma unroll
      for (int r = 0; r < 4; ++r) {
        int f0 = (q << 2) + r;
        offs[row][fr][f0] = oacc0[r] + b_off[f0];
      }
      if (q == 0) {
        offs[row][fr][16] = oacc1[0] + b_off[16];
        offs[row][fr][17] = oacc1[1] + b_off[17];
      }
    }
    __syncthreads();
    if (g == 1) {
#pragma unroll
      for (int r = 0; r < 4; ++r) {
        int f0 = (q << 2) + r;
        offs[row][fr][f0] += oacc0[r];
      }
      if (q == 0) {
        offs[row][fr][16] += oacc1[0];
        offs[row][fr][17] += oacc1[1];
      }
    }
  }
  __syncthreads();

  // -------- Phase B: sampling (2 s-chunks per wave) + full-O MFMA --------
  f32x4_t acc[8];
#pragma unroll
  for (int nf = 0; nf < 8; ++nf) acc[nf] = (f32x4_t){0.f, 0.f, 0.f, 0.f};

  // ---- hoisted escape check: one ballot for all 9 taps ----
  bool any_bad = false;
#pragma unroll
  for (int kt = 0; kt < 9; ++kt) {
    float oy = offs[row][fr][2 * kt];
    float ox = offs[row][fr][2 * kt + 1];
    float py = (float)(ho + kt / 3 - 1) + oy;
    float px = (float)(wo + kt % 3 - 1) + ox;
    int y0 = (int)floorf(py), x0 = (int)floorf(px);
    int y1 = y0 + 1, x1 = x0 + 1;
    int y0c = min(max(y0, 0), H_ - 1), y1c = min(max(y1, 0), H_ - 1);
    int x0c = min(max(x0, 0), W_ - 1), x1c = min(max(x1, 0), W_ - 1);
    any_bad |= (y0c < ys) || (y1c > ye2) || (x0c < xsL) || (x1c > xe2);
  }

  if (__ballot(any_bad) == 0ULL) {
    // ======== FAST PATH: fully branchless, no per-tap control flow ========
#pragma unroll
    for (int kt = 0; kt < 9; ++kt) {
      float oy = offs[row][fr][2 * kt];
      float ox = offs[row][fr][2 * kt + 1];
      float py = (float)(ho + kt / 3 - 1) + oy;
      float px = (float)(wo + kt % 3 - 1) + ox;
      float fy0 = floorf(py), fx0 = floorf(px);
      float dy = py - fy0, dx = px - fx0;
      int y0 = (int)fy0, x0 = (int)fx0;
      int y1 = y0 + 1, x1 = x0 + 1;
      float my0 = (y0 >= 0 && y0 < H_) ? 1.f : 0.f;
      float my1 = (y1 >= 0 && y1 < H_) ? 1.f : 0.f;
      float mx0 = (x0 >= 0 && x0 < W_) ? 1.f : 0.f;
      float mx1 = (x1 >= 0 && x1 < W_) ? 1.f : 0.f;
      float w00 = (1.f - dy) * (1.f - dx) * my0 * mx0;
      float w01 = (1.f - dy) * dx * my0 * mx1;
      float w10 = dy * (1.f - dx) * my1 * mx0;
      float w11 = dy * dx * my1 * mx1;
      int y0c = min(max(y0, 0), H_ - 1), y1c = min(max(y1, 0), H_ - 1);
      int x0c = min(max(x0, 0), W_ - 1), x1c = min(max(x1, 0), W_ - 1);
      int p00 = (y0c - ys) * WC_ + (x0c - xsL), p01 = p00 + (x1c - x0c);
      int p10 = (y1c - ys) * WC_ + (x0c - xsL), p11 = p10 + (x1c - x0c);

      f32x2_t w00p = (f32x2_t){w00, w00}, w01p = (f32x2_t){w01, w01};
      f32x2_t w10p = (f32x2_t){w10, w10}, w11p = (f32x2_t){w11, w11};

      short8_t v00[2], v01[2], v10[2], v11[2];
#pragma unroll
      for (int sh = 0; sh < 2; ++sh) {
        int ch = (((g << 1) | sh) << 2) + q;
        v00[sh] = lds16(xs, p00, ch);
        v01[sh] = lds16(xs, p01, ch);
        v10[sh] = lds16(xs, p10, ch);
        v11[sh] = lds16(xs, p11, ch);
      }

#pragma unroll
      for (int sh = 0; sh < 2; ++sh) {
        int s = (g << 1) | sh;
        uint4_t u00 = __builtin_bit_cast(uint4_t, v00[sh]);
        uint4_t u01 = __builtin_bit_cast(uint4_t, v01[sh]);
        uint4_t u10 = __builtin_bit_cast(uint4_t, v10[sh]);
        uint4_t u11 = __builtin_bit_cast(uint4_t, v11[sh]);
        uint4_t sfu;
#pragma unroll
        for (int d = 0; d < 4; ++d) {
          f32x2_t r = pk_mul(bfpair(u00[d]), w00p);
          r = pk_fma(bfpair(u01[d]), w01p, r);
          r = pk_fma(bfpair(u10[d]), w10p, r);
          r = pk_fma(bfpair(u11[d]), w11p, r);
          unsigned p;
          asm("v_cvt_pk_bf16_f32 %0, %1, %2" : "=v"(p) : "v"(r[0]), "v"(r[1]));
          sfu[d] = p;
        }
        short8_t sf = __builtin_bit_cast(short8_t, sfu);
        int ks = (kt << 2) + s;
        const short* wp = w_bt2 + (((ks << 7) + fr) << 5) + (q << 3);
#pragma unroll
        for (int nf = 0; nf < 8; ++nf) {
          short8_t wf = *(const short8_t*)(wp + (nf << 9));   // +nf*16 o-rows
          acc[nf] = __builtin_amdgcn_mfma_f32_16x16x32_bf16(wf, sf, acc[nf], 0, 0, 0);
        }
      }
    }
  } else {
    // ======== SLOW PATH (cold): r18 per-tap fallback loop, verbatim ========
#pragma unroll
    for (int kt = 0; kt < 9; ++kt) {
      float oy = offs[row][fr][2 * kt];
      float ox = offs[row][fr][2 * kt + 1];
      float py = (float)(ho + kt / 3 - 1) + oy;
      float px = (float)(wo + kt % 3 - 1) + ox;
      float fy0 = floorf(py), fx0 = floorf(px);
      float dy = py - fy0, dx = px - fx0;
      int y0 = (int)fy0, x0 = (int)fx0;
      int y1 = y0 + 1, x1 = x0 + 1;
      float my0 = (y0 >= 0 && y0 < H_) ? 1.f : 0.f;
      float my1 = (y1 >= 0 && y1 < H_) ? 1.f : 0.f;
      float mx0 = (x0 >= 0 && x0 < W_) ? 1.f : 0.f;
      float mx1 = (x1 >= 0 && x1 < W_) ? 1.f : 0.f;
      float w00 = (1.f - dy) * (1.f - dx) * my0 * mx0;
      float w01 = (1.f - dy) * dx * my0 * mx1;
      float w10 = dy * (1.f - dx) * my1 * mx0;
      float w11 = dy * dx * my1 * mx1;
      int y0c = min(max(y0, 0), H_ - 1), y1c = min(max(y1, 0), H_ - 1);
      int x0c = min(max(x0, 0), W_ - 1), x1c = min(max(x1, 0), W_ - 1);
      int p00 = (y0c - ys) * WC_ + (x0c - xsL), p01 = p00 + (x1c - x0c);
      int p10 = (y1c - ys) * WC_ + (x0c - xsL), p11 = p10 + (x1c - x0c);

      f32x2_t w00p = (f32x2_t){w00, w00}, w01p = (f32x2_t){w01, w01};
      f32x2_t w10p = (f32x2_t){w10, w10}, w11p = (f32x2_t){w11, w11};

      short8_t v00[2], v01[2], v10[2], v11[2];
      bool in_win = (y0c >= ys) && (y1c <= ye2) && (x0c >= xsL) && (x1c <= xe2);
      if (in_win) {
#pragma unroll
        for (int sh = 0; sh < 2; ++sh) {
          int ch = (((g << 1) | sh) << 2) + q;
          v00[sh] = lds16(xs, p00, ch);
          v01[sh] = lds16(xs, p01, ch);
          v10[sh] = lds16(xs, p10, ch);
          v11[sh] = lds16(xs, p11, ch);
        }
      } else {                           // per-lane fallback: global gathers
        const short* g00 = xtb + (((y0c << 6) + x0c) << 7);
        const short* g01 = xtb + (((y0c << 6) + x1c) << 7);
        const short* g10 = xtb + (((y1c << 6) + x0c) << 7);
        const short* g11 = xtb + (((y1c << 6) + x1c) << 7);
#pragma unroll
        for (int sh = 0; sh < 2; ++sh) {
          int c0 = (((g << 1) | sh) << 5) + (q << 3);
          v00[sh] = *(const short8_t*)(g00 + c0);
          v01[sh] = *(const short8_t*)(g01 + c0);
          v10[sh] = *(const short8_t*)(g10 + c0);
          v11[sh] = *(const short8_t*)(g11 + c0);
        }
      }

#pragma unroll
      for (int sh = 0; sh < 2; ++sh) {
        int s = (g << 1) | sh;
        uint4_t u00 = __builtin_bit_cast(uint4_t, v00[sh]);
        uint4_t u01 = __builtin_bit_cast(uint4_t, v01[sh]);
        uint4_t u10 = __builtin_bit_cast(uint4_t, v10[sh]);
        uint4_t u11 = __builtin_bit_cast(uint4_t, v11[sh]);
        uint4_t sfu;
#pragma unroll
        for (int d = 0; d < 4; ++d) {
          f32x2_t r = pk_mul(bfpair(u00[d]), w00p);
          r = pk_fma(bfpair(u01[d]), w01p, r);
          r = pk_fma(bfpair(u10[d]), w10p, r);
          r = pk_fma(bfpair(u11[d]), w11p, r);
          unsigned p;
          asm("v_cvt_pk_bf16_f32 %0, %1, %2" : "=v"(p) : "v"(r[0]), "v"(r[1]));
          sfu[d] = p;
        }
        short8_t sf = __builtin_bit_cast(short8_t, sfu);
        int ks = (kt << 2) + s;
        const short* wp = w_bt2 + (((ks << 7) + fr) << 5) + (q << 3);
#pragma unroll
        for (int nf = 0; nf < 8; ++nf) {
          short8_t wf = *(const short8_t*)(wp + (nf << 9));
          acc[nf] = __builtin_amdgcn_mfma_f32_16x16x32_bf16(wf, sf, acc[nf], 0, 0, 0);
        }
      }
    }
  }

  // -------- cross-g reduction through LDS (reuse xs), g0 stores --------
  __syncthreads();                       // xs staging no longer needed
  float* red = (float*)xs;               // [4][16][136] floats = 34816 B
  if (g == 1) {
#pragma unroll
    for (int nf = 0; nf < 8; ++nf) {
      *(f32x4_t*)&red[(row * 16 + fr) * 136 + (nf << 4) + (q << 2)] = acc[nf];
    }
  }
  __syncthreads();
  if (g == 0) {
    float* ob = out + ((long)(b * O_) << 12) + (ho << 6) + wo;
#pragma unroll
    for (int nf = 0; nf < 8; ++nf) {
      f32x4_t other = *(const f32x4_t*)&red[(row * 16 + fr) * 136 + (nf << 4) + (q << 2)];
#pragma unroll
      for (int r = 0; r < 4; ++r) {
        ob[(long)((nf << 4) + (q << 2) + r) << 12] = acc[nf][r] + other[r];
      }
    }
  }
}

extern "C" void kernel_launch(void* const* d_in, const int* in_sizes, int n_in,
                              void* d_out, int out_size, void* d_ws, size_t ws_size,
                              hipStream_t stream) {
  const float* x     = (const float*)d_in[0];
  const float* w_off = (const float*)d_in[1];
  const float* b_off = (const float*)d_in[2];
  const float* w     = (const float*)d_in[3];
  float* out = (float*)d_out;

  short* w_bt2 = (short*)d_ws;                                  // 294912 B
  short* w_ot2 = (short*)((char*)d_ws + 294912);                // 73728 B
  short* x_t   = (short*)((char*)d_ws + 294912 + 73728);        // 8388608 B

  prep_all_kernel<<<1232, 256, 0, stream>>>(w, w_off, x, w_bt2, w_ot2, x_t);
  fused_deform_kernel<<<512, 512, 0, stream>>>(x_t, w_ot2, b_off, w_bt2, out);
}

// Round 24
// 55.599 us; speedup vs baseline: 1.3722x; 1.0749x over previous
//
#include <hip/hip_runtime.h>

#define B_ 8
#define C_ 128
#define H_ 64
#define W_ 64
#define O_ 128
#define F_ 18
#define K2_ 9
#define HW_ 4096
#define CK2_ 1152

#define WR_ 10              // window rows (4-row tile + halo 3/3)
#define WC_ 22              // window cols (16-col tile + halo 3/3)

typedef __attribute__((ext_vector_type(8))) short short8_t;
typedef __attribute__((ext_vector_type(4))) float f32x4_t;
typedef __attribute__((ext_vector_type(2))) float f32x2_t;
typedef __attribute__((ext_vector_type(4))) unsigned int uint4_t;

__device__ inline short bf16r(float f) {
  unsigned u = __builtin_bit_cast(unsigned, f);
  u += 0x7FFFu + ((u >> 16) & 1u);     // round-to-nearest-even
  return (short)(u >> 16);
}
// packed f32 math (VOP3P, CDNA3+)
__device__ inline f32x2_t pk_mul(f32x2_t a, f32x2_t b) {
  f32x2_t d;
  asm("v_pk_mul_f32 %0, %1, %2" : "=v"(d) : "v"(a), "v"(b));
  return d;
}
__device__ inline f32x2_t pk_fma(f32x2_t a, f32x2_t b, f32x2_t c) {
  f32x2_t d;
  asm("v_pk_fma_f32 %0, %1, %2, %3" : "=v"(d) : "v"(a), "v"(b), "v"(c));
  return d;
}
// {lo bf16 as f32, hi bf16 as f32 (raw: low bits = harmless mantissa noise)}
__device__ inline f32x2_t bfpair(unsigned u) {
  return (f32x2_t){__builtin_bit_cast(float, u << 16),
                   __builtin_bit_cast(float, u)};
}

// ---------------- merged prep (ALL bf16 — r12 verbatim) ----------------
__global__ __launch_bounds__(256) void prep_all_kernel(
    const float* __restrict__ w, const float* __restrict__ w_off,
    const float* __restrict__ x,
    short* __restrict__ w_bt2, short* __restrict__ w_ot2,
    short* __restrict__ x_t) {
  __shared__ float tile[128][65];
  int bid = blockIdx.x, t = threadIdx.x;
  if (bid < 576) {
    int i = bid * 256 + t;               // 0..147455 exact
    int kk2 = i & 31, o = (i >> 5) & 127, ks = i >> 12;
    w_bt2[i] = bf16r(w[(o * C_ + (ks & 3) * 32 + kk2) * K2_ + (ks >> 2)]);
  } else if (bid < 720) {
    int i = (bid - 576) * 256 + t;       // 0..36863 exact
    int kk2 = i & 31, f = (i >> 5) & 31, ks = i >> 10;
    w_ot2[i] = (f < F_) ? bf16r(w_off[(f * C_ + (ks & 3) * 32 + kk2) * K2_ + (ks >> 2)])
                        : (short)0;
  } else {
    int xb_id = bid - 720;               // 0..511
    int b = xb_id >> 6;
    int p_base = (xb_id & 63) << 6;
    const float* xb = x + ((long)b << 19);
#pragma unroll
    for (int i = 0; i < 32; ++i) {
      int idx = (i << 8) + t;
      int c = idx >> 6, p = idx & 63;
      tile[c][p] = xb[((long)c << 12) + p_base + p];
    }
    __syncthreads();
#pragma unroll
    for (int i = 0; i < 32; ++i) {
      int idx = (i << 8) + t;
      int p = idx >> 7, c = idx & 127;
      x_t[(((long)(b << 12) + p_base + p) << 7) + c] = bf16r(tile[c][p]);
    }
  }
}

// LDS chunk read: pixel = 256B, 16B chunks XOR-swizzled by pix&15
__device__ inline short8_t lds16(const short* xs, int pix, int ch) {
  return *(const short8_t*)(xs + (pix << 7) + ((ch ^ (pix & 15)) << 3));
}

// ---------------- fused kernel (w-fragment reuse across 2 pos-groups) -------
// block = 512 threads (8 waves) = 4x16 output tile of one batch.
// Phase A roles: (rowA=wv&3, gA=wv>>2) — unchanged, verbatim.
// Phase B roles: (rp=wv&1 row-pair, g=(wv>>1)&1 K-half, h=wv>>2 O-half).
// Each wave: 32 positions (rows 2rp,2rp+1) x 64 o (h-half) x half-K.
// Per tap: blend BOTH row-groups, load the 8 w fragments ONCE (shared) ->
// block w-traffic halves (1.15MB -> 576KB) and ~32 VGPRs free up.
__global__ __launch_bounds__(512, 4) void fused_deform_kernel(
    const short* __restrict__ x_t, const short* __restrict__ w_ot2,
    const float* __restrict__ b_off, const short* __restrict__ w_bt2,
    float* __restrict__ out) {
  __shared__ short xs[WR_ * WC_ * 128];  // 56320 B ; reused as f32 red buffer
  __shared__ float offs[4][16][20];      // 5120 B  ; total 61440 <= 64KB

  int tid = threadIdx.x;
  int wv = tid >> 6, lane = tid & 63;
  int fr = lane & 15, q = lane >> 4;
  int bid = (int)blockIdx.x;
  int b = bid & 7;                       // batch per XCD
  int tile_id = bid >> 3;                // 0..63
  int ho0 = (tile_id >> 2) << 2;         // 4-row strips
  int x0b = (tile_id & 3) << 4;          // 16-col strips
  int ys  = min(max(ho0 - 3, 0), H_ - WR_);   // full 10-row window in-image
  int xsL = min(max(x0b - 3, 0), W_ - WC_);   // full 22-col window in-image
  int ye2 = ys + WR_ - 1, xe2 = xsL + WC_ - 1;

  const short* xtb = x_t + ((long)b << 19);

  // -------- stage window: 10*22 pixels * 16 chunks = 3520 chunks --------
#pragma unroll
  for (int i = 0; i < 7; ++i) {
    int ci = (i << 9) + tid;
    if (ci < WR_ * WC_ * 16) {
      int pix = ci >> 4, ch = ci & 15;
      int yr = pix / WC_, xr = pix - yr * WC_;
      short8_t v = *(const short8_t*)(xtb + ((((ys + yr) << 6) + xsL + xr) << 7) + (ch << 3));
      *(short8_t*)(xs + (pix << 7) + ((ch ^ (pix & 15)) << 3)) = v;
    }
  }
  __syncthreads();

  // -------- Phase A: offset conv via bf16 MFMA (r18 verbatim roles) --------
  {
    int rowA = wv & 3, gA = wv >> 2;
    int hoA = ho0 + rowA;
    int woA = x0b + fr;
    f32x4_t oacc0 = (f32x4_t){0.f, 0.f, 0.f, 0.f};
    f32x4_t oacc1 = (f32x4_t){0.f, 0.f, 0.f, 0.f};
#pragma unroll
    for (int kt = 0; kt < 9; ++kt) {
      int y = hoA + kt / 3 - 1, xx = woA + kt % 3 - 1;
      bool ok = (y >= 0) & (y < H_) & (xx >= 0) & (xx < W_);
      int yc = min(max(y, 0), H_ - 1), xc = min(max(xx, 0), W_ - 1);
      int pixA = (yc - ys) * WC_ + (xc - xsL);
#pragma unroll
      for (int sh = 0; sh < 2; ++sh) {
        int s = (gA << 1) | sh;
        short8_t bfv = lds16(xs, pixA, (s << 2) + q);
        if (!ok) bfv = (short8_t){0, 0, 0, 0, 0, 0, 0, 0};
        int ks = (kt << 2) + s;
        short8_t a0 = *(const short8_t*)(w_ot2 + (((ks << 5) + fr) << 5) + (q << 3));
        short8_t a1 = *(const short8_t*)(w_ot2 + (((ks << 5) + 16 + fr) << 5) + (q << 3));
        oacc0 = __builtin_amdgcn_mfma_f32_16x16x32_bf16(a0, bfv, oacc0, 0, 0, 0);
        oacc1 = __builtin_amdgcn_mfma_f32_16x16x32_bf16(a1, bfv, oacc1, 0, 0, 0);
      }
    }
    if (gA == 0) {
#pragma unroll
      for (int r = 0; r < 4; ++r) {
        int f0 = (q << 2) + r;
        offs[rowA][fr][f0] = oacc0[r] + b_off[f0];
      }
      if (q == 0) {
        offs[rowA][fr][16] = oacc1[0] + b_off[16];
        offs[rowA][fr][17] = oacc1[1] + b_off[17];
      }
    }
    __syncthreads();
    if (gA == 1) {
#pragma unroll
      for (int r = 0; r < 4; ++r) {
        int f0 = (q << 2) + r;
        offs[rowA][fr][f0] += oacc0[r];
      }
      if (q == 0) {
        offs[rowA][fr][16] += oacc1[0];
        offs[rowA][fr][17] += oacc1[1];
      }
    }
  }
  __syncthreads();

  // -------- Phase B: 2 row-groups share w fragments --------
  int rp = wv & 1, g = (wv >> 1) & 1, h = wv >> 2;
  int wo = x0b + fr;

  f32x4_t acc[8];                        // [grp*4 + nf], 32 AGPR
#pragma unroll
  for (int i = 0; i < 8; ++i) acc[i] = (f32x4_t){0.f, 0.f, 0.f, 0.f};

#pragma unroll
  for (int kt = 0; kt < 9; ++kt) {
    short8_t sf[2][2];                   // [grp][sh]
#pragma unroll
    for (int grp = 0; grp < 2; ++grp) {
      int rowg = (rp << 1) | grp;
      int ho = ho0 + rowg;
      float oy = offs[rowg][fr][2 * kt];
      float ox = offs[rowg][fr][2 * kt + 1];
      float py = (float)(ho + kt / 3 - 1) + oy;
      float px = (float)(wo + kt % 3 - 1) + ox;
      float fy0 = floorf(py), fx0 = floorf(px);
      float dy = py - fy0, dx = px - fx0;
      int y0 = (int)fy0, x0 = (int)fx0;
      int y1 = y0 + 1, x1 = x0 + 1;
      float my0 = (y0 >= 0 && y0 < H_) ? 1.f : 0.f;
      float my1 = (y1 >= 0 && y1 < H_) ? 1.f : 0.f;
      float mx0 = (x0 >= 0 && x0 < W_) ? 1.f : 0.f;
      float mx1 = (x1 >= 0 && x1 < W_) ? 1.f : 0.f;
      float w00 = (1.f - dy) * (1.f - dx) * my0 * mx0;
      float w01 = (1.f - dy) * dx * my0 * mx1;
      float w10 = dy * (1.f - dx) * my1 * mx0;
      float w11 = dy * dx * my1 * mx1;
      int y0c = min(max(y0, 0), H_ - 1), y1c = min(max(y1, 0), H_ - 1);
      int x0c = min(max(x0, 0), W_ - 1), x1c = min(max(x1, 0), W_ - 1);
      int p00 = (y0c - ys) * WC_ + (x0c - xsL), p01 = p00 + (x1c - x0c);
      int p10 = (y1c - ys) * WC_ + (x0c - xsL), p11 = p10 + (x1c - x0c);

      f32x2_t w00p = (f32x2_t){w00, w00}, w01p = (f32x2_t){w01, w01};
      f32x2_t w10p = (f32x2_t){w10, w10}, w11p = (f32x2_t){w11, w11};

      short8_t v00[2], v01[2], v10[2], v11[2];
      unsigned long long bad =
          __ballot((y0c < ys) || (y1c > ye2) || (x0c < xsL) || (x1c > xe2));
      if (bad == 0ULL) {
#pragma unroll
        for (int sh = 0; sh < 2; ++sh) {
          int ch = (((g << 1) | sh) << 2) + q;
          v00[sh] = lds16(xs, p00, ch);
          v01[sh] = lds16(xs, p01, ch);
          v10[sh] = lds16(xs, p10, ch);
          v11[sh] = lds16(xs, p11, ch);
        }
      } else {                           // rare fallback: global gathers
        const short* g00 = xtb + (((y0c << 6) + x0c) << 7);
        const short* g01 = xtb + (((y0c << 6) + x1c) << 7);
        const short* g10 = xtb + (((y1c << 6) + x0c) << 7);
        const short* g11 = xtb + (((y1c << 6) + x1c) << 7);
#pragma unroll
        for (int sh = 0; sh < 2; ++sh) {
          int c0 = (((g << 1) | sh) << 5) + (q << 3);
          v00[sh] = *(const short8_t*)(g00 + c0);
          v01[sh] = *(const short8_t*)(g01 + c0);
          v10[sh] = *(const short8_t*)(g10 + c0);
          v11[sh] = *(const short8_t*)(g11 + c0);
        }
      }

#pragma unroll
      for (int sh = 0; sh < 2; ++sh) {
        uint4_t u00 = __builtin_bit_cast(uint4_t, v00[sh]);
        uint4_t u01 = __builtin_bit_cast(uint4_t, v01[sh]);
        uint4_t u10 = __builtin_bit_cast(uint4_t, v10[sh]);
        uint4_t u11 = __builtin_bit_cast(uint4_t, v11[sh]);
        uint4_t sfu;
#pragma unroll
        for (int d = 0; d < 4; ++d) {
          f32x2_t r = pk_mul(bfpair(u00[d]), w00p);
          r = pk_fma(bfpair(u01[d]), w01p, r);
          r = pk_fma(bfpair(u10[d]), w10p, r);
          r = pk_fma(bfpair(u11[d]), w11p, r);
          unsigned p;
          asm("v_cvt_pk_bf16_f32 %0, %1, %2" : "=v"(p) : "v"(r[0]), "v"(r[1]));
          sfu[d] = p;
        }
        sf[grp][sh] = __builtin_bit_cast(short8_t, sfu);
      }
    }

    // ---- w fragments loaded ONCE per tap, shared by both row-groups ----
#pragma unroll
    for (int sh = 0; sh < 2; ++sh) {
      int s = (g << 1) | sh;
      int ks = (kt << 2) + s;
      const short* wp = w_bt2 + (((ks << 7) + (h << 6) + fr) << 5) + (q << 3);
#pragma unroll
      for (int nf = 0; nf < 4; ++nf) {
        short8_t wf = *(const short8_t*)(wp + (nf << 9));   // +nf*16 o-rows
        acc[0 * 4 + nf] = __builtin_amdgcn_mfma_f32_16x16x32_bf16(wf, sf[0][sh], acc[0 * 4 + nf], 0, 0, 0);
        acc[1 * 4 + nf] = __builtin_amdgcn_mfma_f32_16x16x32_bf16(wf, sf[1][sh], acc[1 * 4 + nf], 0, 0, 0);
      }
    }
  }

  // -------- cross-g reduction through LDS (reuse xs) --------
  __syncthreads();                       // xs staging no longer needed
  float* red = (float*)xs;               // 4 zones x [2][16][68] = 34816 B
  int zone = (rp << 1) + h;              // 0..3
  int base = zone * 2176;
  if (g == 1) {
#pragma unroll
    for (int grp = 0; grp < 2; ++grp) {
#pragma unroll
      for (int nf = 0; nf < 4; ++nf) {
        *(f32x4_t*)&red[base + grp * 1088 + fr * 68 + (nf << 4) + (q << 2)] =
            acc[grp * 4 + nf];
      }
    }
  }
  __syncthreads();
  if (g == 0) {
#pragma unroll
    for (int grp = 0; grp < 2; ++grp) {
      int rowg = (rp << 1) | grp;
      int ho = ho0 + rowg;
      float* ob = out + ((long)(b * O_) << 12) + (ho << 6) + wo;
#pragma unroll
      for (int nf = 0; nf < 4; ++nf) {
        f32x4_t other = *(const f32x4_t*)&red[base + grp * 1088 + fr * 68 + (nf << 4) + (q << 2)];
#pragma unroll
        for (int r = 0; r < 4; ++r) {
          ob[(long)(((h << 6) + (nf << 4) + (q << 2) + r)) << 12] =
              acc[grp * 4 + nf][r] + other[r];
        }
      }
    }
  }
}

extern "C" void kernel_launch(void* const* d_in, const int* in_sizes, int n_in,
                              void* d_out, int out_size, void* d_ws, size_t ws_size,
                              hipStream_t stream) {
  const float* x     = (const float*)d_in[0];
  const float* w_off = (const float*)d_in[1];
  const float* b_off = (const float*)d_in[2];
  const float* w     = (const float*)d_in[3];
  float* out = (float*)d_out;

  short* w_bt2 = (short*)d_ws;                                  // 294912 B
  short* w_ot2 = (short*)((char*)d_ws + 294912);                // 73728 B
  short* x_t   = (short*)((char*)d_ws + 294912 + 73728);        // 8388608 B

  prep_all_kernel<<<1232, 256, 0, stream>>>(w, w_off, x, w_bt2, w_ot2, x_t);
  fused_deform_kernel<<<512, 512, 0, stream>>>(x_t, w_ot2, b_off, w_bt2, out);
}

// Round 25
// 54.699 us; speedup vs baseline: 1.3948x; 1.0165x over previous
//
#include <hip/hip_runtime.h>

#define B_ 8
#define C_ 128
#define H_ 64
#define W_ 64
#define O_ 128
#define F_ 18
#define K2_ 9
#define HW_ 4096
#define CK2_ 1152

#define WR_ 10              // window rows (4-row tile + halo 3/3)
#define WC_ 22              // window cols (16-col tile + halo 3/3)

typedef __attribute__((ext_vector_type(8))) short short8_t;
typedef __attribute__((ext_vector_type(4))) float f32x4_t;
typedef __attribute__((ext_vector_type(2))) float f32x2_t;
typedef __attribute__((ext_vector_type(4))) unsigned int uint4_t;

__device__ inline short bf16r(float f) {
  unsigned u = __builtin_bit_cast(unsigned, f);
  u += 0x7FFFu + ((u >> 16) & 1u);     // round-to-nearest-even
  return (short)(u >> 16);
}
// packed f32 math (VOP3P, CDNA3+)
__device__ inline f32x2_t pk_mul(f32x2_t a, f32x2_t b) {
  f32x2_t d;
  asm("v_pk_mul_f32 %0, %1, %2" : "=v"(d) : "v"(a), "v"(b));
  return d;
}
__device__ inline f32x2_t pk_fma(f32x2_t a, f32x2_t b, f32x2_t c) {
  f32x2_t d;
  asm("v_pk_fma_f32 %0, %1, %2, %3" : "=v"(d) : "v"(a), "v"(b), "v"(c));
  return d;
}
// {lo bf16 as f32, hi bf16 as f32 (raw: low bits = harmless mantissa noise)}
__device__ inline f32x2_t bfpair(unsigned u) {
  return (f32x2_t){__builtin_bit_cast(float, u << 16),
                   __builtin_bit_cast(float, u)};
}

// ---------------- merged prep (ALL bf16 — r12 verbatim) ----------------
__global__ __launch_bounds__(256) void prep_all_kernel(
    const float* __restrict__ w, const float* __restrict__ w_off,
    const float* __restrict__ x,
    short* __restrict__ w_bt2, short* __restrict__ w_ot2,
    short* __restrict__ x_t) {
  __shared__ float tile[128][65];
  int bid = blockIdx.x, t = threadIdx.x;
  if (bid < 576) {
    int i = bid * 256 + t;               // 0..147455 exact
    int kk2 = i & 31, o = (i >> 5) & 127, ks = i >> 12;
    w_bt2[i] = bf16r(w[(o * C_ + (ks & 3) * 32 + kk2) * K2_ + (ks >> 2)]);
  } else if (bid < 720) {
    int i = (bid - 576) * 256 + t;       // 0..36863 exact
    int kk2 = i & 31, f = (i >> 5) & 31, ks = i >> 10;
    w_ot2[i] = (f < F_) ? bf16r(w_off[(f * C_ + (ks & 3) * 32 + kk2) * K2_ + (ks >> 2)])
                        : (short)0;
  } else {
    int xb_id = bid - 720;               // 0..511
    int b = xb_id >> 6;
    int p_base = (xb_id & 63) << 6;
    const float* xb = x + ((long)b << 19);
#pragma unroll
    for (int i = 0; i < 32; ++i) {
      int idx = (i << 8) + t;
      int c = idx >> 6, p = idx & 63;
      tile[c][p] = xb[((long)c << 12) + p_base + p];
    }
    __syncthreads();
#pragma unroll
    for (int i = 0; i < 32; ++i) {
      int idx = (i << 8) + t;
      int p = idx >> 7, c = idx & 127;
      x_t[(((long)(b << 12) + p_base + p) << 7) + c] = bf16r(tile[c][p]);
    }
  }
}

// LDS chunk read: pixel = 256B, 16B chunks XOR-swizzled by pix&15
__device__ inline short8_t lds16(const short* xs, int pix, int ch) {
  return *(const short8_t*)(xs + (pix << 7) + ((ch ^ (pix & 15)) << 3));
}

// ---------------- fused kernel (r24 + de-spilled tap inner) -----------------
// block = 512 threads (8 waves) = 4x16 output tile of one batch.
// Phase A roles: (rowA=wv&3, gA=wv>>2) — r18 verbatim.
// Phase B roles: (rp=wv&1 row-pair, g=(wv>>1)&1 K-half, h=wv>>2 O-half).
// Per tap: load the 8 w fragments ONCE (wf[2][4], 32 VGPR), then process
// row-group 0 and 1 SEQUENTIALLY (blend -> 8 MFMA each) so only one group's
// sampling state is live at a time -> no scratch spill, w-traffic still 2x cut.
__global__ __launch_bounds__(512, 4) void fused_deform_kernel(
    const short* __restrict__ x_t, const short* __restrict__ w_ot2,
    const float* __restrict__ b_off, const short* __restrict__ w_bt2,
    float* __restrict__ out) {
  __shared__ short xs[WR_ * WC_ * 128];  // 56320 B ; reused as f32 red buffer
  __shared__ float offs[4][16][20];      // 5120 B  ; total 61440 <= 64KB

  int tid = threadIdx.x;
  int wv = tid >> 6, lane = tid & 63;
  int fr = lane & 15, q = lane >> 4;
  int bid = (int)blockIdx.x;
  int b = bid & 7;                       // batch per XCD
  int tile_id = bid >> 3;                // 0..63
  int ho0 = (tile_id >> 2) << 2;         // 4-row strips
  int x0b = (tile_id & 3) << 4;          // 16-col strips
  int ys  = min(max(ho0 - 3, 0), H_ - WR_);   // full 10-row window in-image
  int xsL = min(max(x0b - 3, 0), W_ - WC_);   // full 22-col window in-image
  int ye2 = ys + WR_ - 1, xe2 = xsL + WC_ - 1;

  const short* xtb = x_t + ((long)b << 19);

  // -------- stage window: 10*22 pixels * 16 chunks = 3520 chunks --------
#pragma unroll
  for (int i = 0; i < 7; ++i) {
    int ci = (i << 9) + tid;
    if (ci < WR_ * WC_ * 16) {
      int pix = ci >> 4, ch = ci & 15;
      int yr = pix / WC_, xr = pix - yr * WC_;
      short8_t v = *(const short8_t*)(xtb + ((((ys + yr) << 6) + xsL + xr) << 7) + (ch << 3));
      *(short8_t*)(xs + (pix << 7) + ((ch ^ (pix & 15)) << 3)) = v;
    }
  }
  __syncthreads();

  // -------- Phase A: offset conv via bf16 MFMA (r18 verbatim roles) --------
  {
    int rowA = wv & 3, gA = wv >> 2;
    int hoA = ho0 + rowA;
    int woA = x0b + fr;
    f32x4_t oacc0 = (f32x4_t){0.f, 0.f, 0.f, 0.f};
    f32x4_t oacc1 = (f32x4_t){0.f, 0.f, 0.f, 0.f};
#pragma unroll
    for (int kt = 0; kt < 9; ++kt) {
      int y = hoA + kt / 3 - 1, xx = woA + kt % 3 - 1;
      bool ok = (y >= 0) & (y < H_) & (xx >= 0) & (xx < W_);
      int yc = min(max(y, 0), H_ - 1), xc = min(max(xx, 0), W_ - 1);
      int pixA = (yc - ys) * WC_ + (xc - xsL);
#pragma unroll
      for (int sh = 0; sh < 2; ++sh) {
        int s = (gA << 1) | sh;
        short8_t bfv = lds16(xs, pixA, (s << 2) + q);
        if (!ok) bfv = (short8_t){0, 0, 0, 0, 0, 0, 0, 0};
        int ks = (kt << 2) + s;
        short8_t a0 = *(const short8_t*)(w_ot2 + (((ks << 5) + fr) << 5) + (q << 3));
        short8_t a1 = *(const short8_t*)(w_ot2 + (((ks << 5) + 16 + fr) << 5) + (q << 3));
        oacc0 = __builtin_amdgcn_mfma_f32_16x16x32_bf16(a0, bfv, oacc0, 0, 0, 0);
        oacc1 = __builtin_amdgcn_mfma_f32_16x16x32_bf16(a1, bfv, oacc1, 0, 0, 0);
      }
    }
    if (gA == 0) {
#pragma unroll
      for (int r = 0; r < 4; ++r) {
        int f0 = (q << 2) + r;
        offs[rowA][fr][f0] = oacc0[r] + b_off[f0];
      }
      if (q == 0) {
        offs[rowA][fr][16] = oacc1[0] + b_off[16];
        offs[rowA][fr][17] = oacc1[1] + b_off[17];
      }
    }
    __syncthreads();
    if (gA == 1) {
#pragma unroll
      for (int r = 0; r < 4; ++r) {
        int f0 = (q << 2) + r;
        offs[rowA][fr][f0] += oacc0[r];
      }
      if (q == 0) {
        offs[rowA][fr][16] += oacc1[0];
        offs[rowA][fr][17] += oacc1[1];
      }
    }
  }
  __syncthreads();

  // -------- Phase B: 2 row-groups share w fragments (sequential grp) --------
  int rp = wv & 1, g = (wv >> 1) & 1, h = wv >> 2;
  int wo = x0b + fr;

  f32x4_t acc[8];                        // [grp*4 + nf], 32 AGPR
#pragma unroll
  for (int i = 0; i < 8; ++i) acc[i] = (f32x4_t){0.f, 0.f, 0.f, 0.f};

#pragma unroll
  for (int kt = 0; kt < 9; ++kt) {
    // ---- w fragments loaded ONCE per tap (shared by both row-groups) ----
    short8_t wf[2][4];
#pragma unroll
    for (int sh = 0; sh < 2; ++sh) {
      int ks = (kt << 2) + ((g << 1) | sh);
      const short* wp = w_bt2 + (((ks << 7) + (h << 6) + fr) << 5) + (q << 3);
#pragma unroll
      for (int nf = 0; nf < 4; ++nf) {
        wf[sh][nf] = *(const short8_t*)(wp + (nf << 9));   // +nf*16 o-rows
      }
    }

#pragma unroll
    for (int grp = 0; grp < 2; ++grp) {
      int rowg = (rp << 1) | grp;
      int ho = ho0 + rowg;
      float oy = offs[rowg][fr][2 * kt];
      float ox = offs[rowg][fr][2 * kt + 1];
      float py = (float)(ho + kt / 3 - 1) + oy;
      float px = (float)(wo + kt % 3 - 1) + ox;
      float fy0 = floorf(py), fx0 = floorf(px);
      float dy = py - fy0, dx = px - fx0;
      int y0 = (int)fy0, x0 = (int)fx0;
      int y1 = y0 + 1, x1 = x0 + 1;
      float my0 = (y0 >= 0 && y0 < H_) ? 1.f : 0.f;
      float my1 = (y1 >= 0 && y1 < H_) ? 1.f : 0.f;
      float mx0 = (x0 >= 0 && x0 < W_) ? 1.f : 0.f;
      float mx1 = (x1 >= 0 && x1 < W_) ? 1.f : 0.f;
      float w00 = (1.f - dy) * (1.f - dx) * my0 * mx0;
      float w01 = (1.f - dy) * dx * my0 * mx1;
      float w10 = dy * (1.f - dx) * my1 * mx0;
      float w11 = dy * dx * my1 * mx1;
      int y0c = min(max(y0, 0), H_ - 1), y1c = min(max(y1, 0), H_ - 1);
      int x0c = min(max(x0, 0), W_ - 1), x1c = min(max(x1, 0), W_ - 1);
      int p00 = (y0c - ys) * WC_ + (x0c - xsL), p01 = p00 + (x1c - x0c);
      int p10 = (y1c - ys) * WC_ + (x0c - xsL), p11 = p10 + (x1c - x0c);

      f32x2_t w00p = (f32x2_t){w00, w00}, w01p = (f32x2_t){w01, w01};
      f32x2_t w10p = (f32x2_t){w10, w10}, w11p = (f32x2_t){w11, w11};

      short8_t v00[2], v01[2], v10[2], v11[2];
      unsigned long long bad =
          __ballot((y0c < ys) || (y1c > ye2) || (x0c < xsL) || (x1c > xe2));
      if (bad == 0ULL) {
#pragma unroll
        for (int sh = 0; sh < 2; ++sh) {
          int ch = (((g << 1) | sh) << 2) + q;
          v00[sh] = lds16(xs, p00, ch);
          v01[sh] = lds16(xs, p01, ch);
          v10[sh] = lds16(xs, p10, ch);
          v11[sh] = lds16(xs, p11, ch);
        }
      } else {                           // rare fallback: global gathers
        const short* g00 = xtb + (((y0c << 6) + x0c) << 7);
        const short* g01 = xtb + (((y0c << 6) + x1c) << 7);
        const short* g10 = xtb + (((y1c << 6) + x0c) << 7);
        const short* g11 = xtb + (((y1c << 6) + x1c) << 7);
#pragma unroll
        for (int sh = 0; sh < 2; ++sh) {
          int c0 = (((g << 1) | sh) << 5) + (q << 3);
          v00[sh] = *(const short8_t*)(g00 + c0);
          v01[sh] = *(const short8_t*)(g01 + c0);
          v10[sh] = *(const short8_t*)(g10 + c0);
          v11[sh] = *(const short8_t*)(g11 + c0);
        }
      }

#pragma unroll
      for (int sh = 0; sh < 2; ++sh) {
        uint4_t u00 = __builtin_bit_cast(uint4_t, v00[sh]);
        uint4_t u01 = __builtin_bit_cast(uint4_t, v01[sh]);
        uint4_t u10 = __builtin_bit_cast(uint4_t, v10[sh]);
        uint4_t u11 = __builtin_bit_cast(uint4_t, v11[sh]);
        uint4_t sfu;
#pragma unroll
        for (int d = 0; d < 4; ++d) {
          f32x2_t r = pk_mul(bfpair(u00[d]), w00p);
          r = pk_fma(bfpair(u01[d]), w01p, r);
          r = pk_fma(bfpair(u10[d]), w10p, r);
          r = pk_fma(bfpair(u11[d]), w11p, r);
          unsigned p;
          asm("v_cvt_pk_bf16_f32 %0, %1, %2" : "=v"(p) : "v"(r[0]), "v"(r[1]));
          sfu[d] = p;
        }
        short8_t sf = __builtin_bit_cast(short8_t, sfu);
#pragma unroll
        for (int nf = 0; nf < 4; ++nf) {
          acc[grp * 4 + nf] = __builtin_amdgcn_mfma_f32_16x16x32_bf16(
              wf[sh][nf], sf, acc[grp * 4 + nf], 0, 0, 0);
        }
      }
    }
  }

  // -------- cross-g reduction through LDS (reuse xs) --------
  __syncthreads();                       // xs staging no longer needed
  float* red = (float*)xs;               // 4 zones x [2][16][68] = 34816 B
  int zone = (rp << 1) + h;              // 0..3
  int base = zone * 2176;
  if (g == 1) {
#pragma unroll
    for (int grp = 0; grp < 2; ++grp) {
#pragma unroll
      for (int nf = 0; nf < 4; ++nf) {
        *(f32x4_t*)&red[base + grp * 1088 + fr * 68 + (nf << 4) + (q << 2)] =
            acc[grp * 4 + nf];
      }
    }
  }
  __syncthreads();
  if (g == 0) {
#pragma unroll
    for (int grp = 0; grp < 2; ++grp) {
      int rowg = (rp << 1) | grp;
      int ho = ho0 + rowg;
      float* ob = out + ((long)(b * O_) << 12) + (ho << 6) + wo;
#pragma unroll
      for (int nf = 0; nf < 4; ++nf) {
        f32x4_t other = *(const f32x4_t*)&red[base + grp * 1088 + fr * 68 + (nf << 4) + (q << 2)];
#pragma unroll
        for (int r = 0; r < 4; ++r) {
          ob[(long)(((h << 6) + (nf << 4) + (q << 2) + r)) << 12] =
              acc[grp * 4 + nf][r] + other[r];
        }
      }
    }
  }
}

extern "C" void kernel_launch(void* const* d_in, const int* in_sizes, int n_in,
                              void* d_out, int out_size, void* d_ws, size_t ws_size,
                              hipStream_t stream) {
  const float* x     = (const float*)d_in[0];
  const float* w_off = (const float*)d_in[1];
  const float* b_off = (const float*)d_in[2];
  const float* w     = (const float*)d_in[3];
  float* out = (float*)d_out;

  short* w_bt2 = (short*)d_ws;                                  // 294912 B
  short* w_ot2 = (short*)((char*)d_ws + 294912);                // 73728 B
  short* x_t   = (short*)((char*)d_ws + 294912 + 73728);        // 8388608 B

  prep_all_kernel<<<1232, 256, 0, stream>>>(w, w_off, x, w_bt2, w_ot2, x_t);
  fused_deform_kernel<<<512, 512, 0, stream>>>(x_t, w_ot2, b_off, w_bt2, out);
}

// Round 27
// 54.577 us; speedup vs baseline: 1.3979x; 1.0022x over previous
//
#include <hip/hip_runtime.h>

#define B_ 8
#define C_ 128
#define H_ 64
#define W_ 64
#define O_ 128
#define F_ 18
#define K2_ 9
#define HW_ 4096
#define CK2_ 1152

#define WR_ 10              // window rows (4-row tile + halo 3/3)
#define WC_ 22              // window cols (16-col tile + halo 3/3)

typedef __attribute__((ext_vector_type(8))) short short8_t;
typedef __attribute__((ext_vector_type(4))) float f32x4_t;
typedef __attribute__((ext_vector_type(2))) float f32x2_t;
typedef __attribute__((ext_vector_type(4))) unsigned int uint4_t;

__device__ inline short bf16r(float f) {
  unsigned u = __builtin_bit_cast(unsigned, f);
  u += 0x7FFFu + ((u >> 16) & 1u);     // round-to-nearest-even
  return (short)(u >> 16);
}
// packed f32 math (VOP3P, CDNA3+)
__device__ inline f32x2_t pk_mul(f32x2_t a, f32x2_t b) {
  f32x2_t d;
  asm("v_pk_mul_f32 %0, %1, %2" : "=v"(d) : "v"(a), "v"(b));
  return d;
}
__device__ inline f32x2_t pk_fma(f32x2_t a, f32x2_t b, f32x2_t c) {
  f32x2_t d;
  asm("v_pk_fma_f32 %0, %1, %2, %3" : "=v"(d) : "v"(a), "v"(b), "v"(c));
  return d;
}
// {lo bf16 as f32, hi bf16 as f32 (raw: low bits = harmless mantissa noise)}
__device__ inline f32x2_t bfpair(unsigned u) {
  return (f32x2_t){__builtin_bit_cast(float, u << 16),
                   __builtin_bit_cast(float, u)};
}

// ---------------- merged prep (ALL bf16) ----------------
__global__ __launch_bounds__(256) void prep_all_kernel(
    const float* __restrict__ w, const float* __restrict__ w_off,
    const float* __restrict__ x,
    short* __restrict__ w_bt2, short* __restrict__ w_ot2,
    short* __restrict__ x_t) {
  __shared__ float tile[128][65];
  int bid = blockIdx.x, t = threadIdx.x;
  if (bid < 576) {
    int i = bid * 256 + t;               // 0..147455 exact
    int kk2 = i & 31, o = (i >> 5) & 127, ks = i >> 12;
    w_bt2[i] = bf16r(w[(o * C_ + (ks & 3) * 32 + kk2) * K2_ + (ks >> 2)]);
  } else if (bid < 720) {
    int i = (bid - 576) * 256 + t;       // 0..36863 exact
    int kk2 = i & 31, f = (i >> 5) & 31, ks = i >> 10;
    w_ot2[i] = (f < F_) ? bf16r(w_off[(f * C_ + (ks & 3) * 32 + kk2) * K2_ + (ks >> 2)])
                        : (short)0;
  } else {
    int xb_id = bid - 720;               // 0..511
    int b = xb_id >> 6;
    int p_base = (xb_id & 63) << 6;
    const float* xb = x + ((long)b << 19);
#pragma unroll
    for (int i = 0; i < 32; ++i) {
      int idx = (i << 8) + t;
      int c = idx >> 6, p = idx & 63;
      tile[c][p] = xb[((long)c << 12) + p_base + p];
    }
    __syncthreads();
#pragma unroll
    for (int i = 0; i < 32; ++i) {
      int idx = (i << 8) + t;
      int p = idx >> 7, c = idx & 127;
      x_t[(((long)(b << 12) + p_base + p) << 7) + c] = bf16r(tile[c][p]);
    }
  }
}

// LDS chunk read: pixel = 256B, 16B chunks XOR-swizzled by pix&15
__device__ inline short8_t lds16(const short* xs, int pix, int ch) {
  return *(const short8_t*)(xs + (pix << 7) + ((ch ^ (pix & 15)) << 3));
}

// ---------------- fused kernel (r25: w-fragment reuse, sequential grp) ------
// block = 512 threads (8 waves) = 4x16 output tile of one batch.
// Phase A roles: (rowA=wv&3, gA=wv>>2).
// Phase B roles: (rp=wv&1 row-pair, g=(wv>>1)&1 K-half, h=wv>>2 O-half).
// Per tap: load the 8 w fragments ONCE (wf[2][4]), then process row-group 0
// and 1 SEQUENTIALLY (blend -> MFMA each) — w-traffic halved vs r18.
__global__ __launch_bounds__(512, 4) void fused_deform_kernel(
    const short* __restrict__ x_t, const short* __restrict__ w_ot2,
    const float* __restrict__ b_off, const short* __restrict__ w_bt2,
    float* __restrict__ out) {
  __shared__ short xs[WR_ * WC_ * 128];  // 56320 B ; reused as f32 red buffer
  __shared__ float offs[4][16][20];      // 5120 B  ; total 61440 <= 64KB

  int tid = threadIdx.x;
  int wv = tid >> 6, lane = tid & 63;
  int fr = lane & 15, q = lane >> 4;
  int bid = (int)blockIdx.x;
  int b = bid & 7;                       // batch per XCD
  int tile_id = bid >> 3;                // 0..63
  int ho0 = (tile_id >> 2) << 2;         // 4-row strips
  int x0b = (tile_id & 3) << 4;          // 16-col strips
  int ys  = min(max(ho0 - 3, 0), H_ - WR_);   // full 10-row window in-image
  int xsL = min(max(x0b - 3, 0), W_ - WC_);   // full 22-col window in-image
  int ye2 = ys + WR_ - 1, xe2 = xsL + WC_ - 1;

  const short* xtb = x_t + ((long)b << 19);

  // -------- stage window: 10*22 pixels * 16 chunks = 3520 chunks --------
#pragma unroll
  for (int i = 0; i < 7; ++i) {
    int ci = (i << 9) + tid;
    if (ci < WR_ * WC_ * 16) {
      int pix = ci >> 4, ch = ci & 15;
      int yr = pix / WC_, xr = pix - yr * WC_;
      short8_t v = *(const short8_t*)(xtb + ((((ys + yr) << 6) + xsL + xr) << 7) + (ch << 3));
      *(short8_t*)(xs + (pix << 7) + ((ch ^ (pix & 15)) << 3)) = v;
    }
  }
  __syncthreads();

  // -------- Phase A: offset conv via bf16 MFMA --------
  {
    int rowA = wv & 3, gA = wv >> 2;
    int hoA = ho0 + rowA;
    int woA = x0b + fr;
    f32x4_t oacc0 = (f32x4_t){0.f, 0.f, 0.f, 0.f};
    f32x4_t oacc1 = (f32x4_t){0.f, 0.f, 0.f, 0.f};
#pragma unroll
    for (int kt = 0; kt < 9; ++kt) {
      int y = hoA + kt / 3 - 1, xx = woA + kt % 3 - 1;
      bool ok = (y >= 0) & (y < H_) & (xx >= 0) & (xx < W_);
      int yc = min(max(y, 0), H_ - 1), xc = min(max(xx, 0), W_ - 1);
      int pixA = (yc - ys) * WC_ + (xc - xsL);
#pragma unroll
      for (int sh = 0; sh < 2; ++sh) {
        int s = (gA << 1) | sh;
        short8_t bfv = lds16(xs, pixA, (s << 2) + q);
        if (!ok) bfv = (short8_t){0, 0, 0, 0, 0, 0, 0, 0};
        int ks = (kt << 2) + s;
        short8_t a0 = *(const short8_t*)(w_ot2 + (((ks << 5) + fr) << 5) + (q << 3));
        short8_t a1 = *(const short8_t*)(w_ot2 + (((ks << 5) + 16 + fr) << 5) + (q << 3));
        oacc0 = __builtin_amdgcn_mfma_f32_16x16x32_bf16(a0, bfv, oacc0, 0, 0, 0);
        oacc1 = __builtin_amdgcn_mfma_f32_16x16x32_bf16(a1, bfv, oacc1, 0, 0, 0);
      }
    }
    if (gA == 0) {
#pragma unroll
      for (int r = 0; r < 4; ++r) {
        int f0 = (q << 2) + r;
        offs[rowA][fr][f0] = oacc0[r] + b_off[f0];
      }
      if (q == 0) {
        offs[rowA][fr][16] = oacc1[0] + b_off[16];
        offs[rowA][fr][17] = oacc1[1] + b_off[17];
      }
    }
    __syncthreads();
    if (gA == 1) {
#pragma unroll
      for (int r = 0; r < 4; ++r) {
        int f0 = (q << 2) + r;
        offs[rowA][fr][f0] += oacc0[r];
      }
      if (q == 0) {
        offs[rowA][fr][16] += oacc1[0];
        offs[rowA][fr][17] += oacc1[1];
      }
    }
  }
  __syncthreads();

  // -------- Phase B: 2 row-groups share w fragments (sequential grp) --------
  int rp = wv & 1, g = (wv >> 1) & 1, h = wv >> 2;
  int wo = x0b + fr;

  f32x4_t acc[8];                        // [grp*4 + nf], 32 AGPR
#pragma unroll
  for (int i = 0; i < 8; ++i) acc[i] = (f32x4_t){0.f, 0.f, 0.f, 0.f};

#pragma unroll
  for (int kt = 0; kt < 9; ++kt) {
    // ---- w fragments loaded ONCE per tap (shared by both row-groups) ----
    short8_t wf[2][4];
#pragma unroll
    for (int sh = 0; sh < 2; ++sh) {
      int ks = (kt << 2) + ((g << 1) | sh);
      const short* wp = w_bt2 + (((ks << 7) + (h << 6) + fr) << 5) + (q << 3);
#pragma unroll
      for (int nf = 0; nf < 4; ++nf) {
        wf[sh][nf] = *(const short8_t*)(wp + (nf << 9));   // +nf*16 o-rows
      }
    }

#pragma unroll
    for (int grp = 0; grp < 2; ++grp) {
      int rowg = (rp << 1) | grp;
      int ho = ho0 + rowg;
      float oy = offs[rowg][fr][2 * kt];
      float ox = offs[rowg][fr][2 * kt + 1];
      float py = (float)(ho + kt / 3 - 1) + oy;
      float px = (float)(wo + kt % 3 - 1) + ox;
      float fy0 = floorf(py), fx0 = floorf(px);
      float dy = py - fy0, dx = px - fx0;
      int y0 = (int)fy0, x0 = (int)fx0;
      int y1 = y0 + 1, x1 = x0 + 1;
      float my0 = (y0 >= 0 && y0 < H_) ? 1.f : 0.f;
      float my1 = (y1 >= 0 && y1 < H_) ? 1.f : 0.f;
      float mx0 = (x0 >= 0 && x0 < W_) ? 1.f : 0.f;
      float mx1 = (x1 >= 0 && x1 < W_) ? 1.f : 0.f;
      float w00 = (1.f - dy) * (1.f - dx) * my0 * mx0;
      float w01 = (1.f - dy) * dx * my0 * mx1;
      float w10 = dy * (1.f - dx) * my1 * mx0;
      float w11 = dy * dx * my1 * mx1;
      int y0c = min(max(y0, 0), H_ - 1), y1c = min(max(y1, 0), H_ - 1);
      int x0c = min(max(x0, 0), W_ - 1), x1c = min(max(x1, 0), W_ - 1);
      int p00 = (y0c - ys) * WC_ + (x0c - xsL), p01 = p00 + (x1c - x0c);
      int p10 = (y1c - ys) * WC_ + (x0c - xsL), p11 = p10 + (x1c - x0c);

      f32x2_t w00p = (f32x2_t){w00, w00}, w01p = (f32x2_t){w01, w01};
      f32x2_t w10p = (f32x2_t){w10, w10}, w11p = (f32x2_t){w11, w11};

      short8_t v00[2], v01[2], v10[2], v11[2];
      unsigned long long bad =
          __ballot((y0c < ys) || (y1c > ye2) || (x0c < xsL) || (x1c > xe2));
      if (bad == 0ULL) {
#pragma unroll
        for (int sh = 0; sh < 2; ++sh) {
          int ch = (((g << 1) | sh) << 2) + q;
          v00[sh] = lds16(xs, p00, ch);
          v01[sh] = lds16(xs, p01, ch);
          v10[sh] = lds16(xs, p10, ch);
          v11[sh] = lds16(xs, p11, ch);
        }
      } else {                           // rare fallback: global gathers
        const short* g00 = xtb + (((y0c << 6) + x0c) << 7);
        const short* g01 = xtb + (((y0c << 6) + x1c) << 7);
        const short* g10 = xtb + (((y1c << 6) + x0c) << 7);
        const short* g11 = xtb + (((y1c << 6) + x1c) << 7);
#pragma unroll
        for (int sh = 0; sh < 2; ++sh) {
          int c0 = (((g << 1) | sh) << 5) + (q << 3);
          v00[sh] = *(const short8_t*)(g00 + c0);
          v01[sh] = *(const short8_t*)(g01 + c0);
          v10[sh] = *(const short8_t*)(g10 + c0);
          v11[sh] = *(const short8_t*)(g11 + c0);
        }
      }

#pragma unroll
      for (int sh = 0; sh < 2; ++sh) {
        uint4_t u00 = __builtin_bit_cast(uint4_t, v00[sh]);
        uint4_t u01 = __builtin_bit_cast(uint4_t, v01[sh]);
        uint4_t u10 = __builtin_bit_cast(uint4_t, v10[sh]);
        uint4_t u11 = __builtin_bit_cast(uint4_t, v11[sh]);
        uint4_t sfu;
#pragma unroll
        for (int d = 0; d < 4; ++d) {
          f32x2_t r = pk_mul(bfpair(u00[d]), w00p);
          r = pk_fma(bfpair(u01[d]), w01p, r);
          r = pk_fma(bfpair(u10[d]), w10p, r);
          r = pk_fma(bfpair(u11[d]), w11p, r);
          unsigned p;
          asm("v_cvt_pk_bf16_f32 %0, %1, %2" : "=v"(p) : "v"(r[0]), "v"(r[1]));
          sfu[d] = p;
        }
        short8_t sf = __builtin_bit_cast(short8_t, sfu);
#pragma unroll
        for (int nf = 0; nf < 4; ++nf) {
          acc[grp * 4 + nf] = __builtin_amdgcn_mfma_f32_16x16x32_bf16(
              wf[sh][nf], sf, acc[grp * 4 + nf], 0, 0, 0);
        }
      }
    }
  }

  // -------- cross-g reduction through LDS (reuse xs) --------
  __syncthreads();                       // xs staging no longer needed
  float* red = (float*)xs;               // 4 zones x [2][16][68] = 34816 B
  int zone = (rp << 1) + h;              // 0..3
  int base = zone * 2176;
  if (g == 1) {
#pragma unroll
    for (int grp = 0; grp < 2; ++grp) {
#pragma unroll
      for (int nf = 0; nf < 4; ++nf) {
        *(f32x4_t*)&red[base + grp * 1088 + fr * 68 + (nf << 4) + (q << 2)] =
            acc[grp * 4 + nf];
      }
    }
  }
  __syncthreads();
  if (g == 0) {
#pragma unroll
    for (int grp = 0; grp < 2; ++grp) {
      int rowg = (rp << 1) | grp;
      int ho = ho0 + rowg;
      float* ob = out + ((long)(b * O_) << 12) + (ho << 6) + wo;
#pragma unroll
      for (int nf = 0; nf < 4; ++nf) {
        f32x4_t other = *(const f32x4_t*)&red[base + grp * 1088 + fr * 68 + (nf << 4) + (q << 2)];
#pragma unroll
        for (int r = 0; r < 4; ++r) {
          ob[(long)(((h << 6) + (nf << 4) + (q << 2) + r)) << 12] =
              acc[grp * 4 + nf][r] + other[r];
        }
      }
    }
  }
}

extern "C" void kernel_launch(void* const* d_in, const int* in_sizes, int n_in,
                              void* d_out, int out_size, void* d_ws, size_t ws_size,
                              hipStream_t stream) {
  const float* x     = (const float*)d_in[0];
  const float* w_off = (const float*)d_in[1];
  const float* b_off = (const float*)d_in[2];
  const float* w     = (const float*)d_in[3];
  float* out = (float*)d_out;

  short* w_bt2 = (short*)d_ws;                                  // 294912 B
  short* w_ot2 = (short*)((char*)d_ws + 294912);                // 73728 B
  short* x_t   = (short*)((char*)d_ws + 294912 + 73728);        // 8388608 B

  prep_all_kernel<<<1232, 256, 0, stream>>>(w, w_off, x, w_bt2, w_ot2, x_t);
  fused_deform_kernel<<<512, 512, 0, stream>>>(x_t, w_ot2, b_off, w_bt2, out);
}